// Round 1
// 1001.866 us; speedup vs baseline: 1.0034x; 1.0034x over previous
//
#include <hip/hip_runtime.h>
#include <hip/hip_bf16.h>

#define NN 100000
#define NNP 100096   // padded rows: multiple of 256
#define NE 1600000
#define FIN 500
#define HID 128

typedef __attribute__((ext_vector_type(8))) short short8;   // 8 bf16 = 4 VGPRs (MFMA A/B frag)
typedef __attribute__((ext_vector_type(4))) float f32x4;    // MFMA C/D frag

__device__ __forceinline__ float bf2f(unsigned short u) {
    return __uint_as_float(((unsigned int)u) << 16);
}
__device__ __forceinline__ unsigned short f2bf(float f) {
    __hip_bfloat16 h = __float2bfloat16(f);
    return *(unsigned short*)&h;
}
__device__ __forceinline__ float lo16(unsigned int v) { return __uint_as_float(v << 16); }
__device__ __forceinline__ float hi16(unsigned int v) { return __uint_as_float(v & 0xffff0000u); }

// ---------- template-named kernel (serves as cnt zeroing) ----------

__global__ __launch_bounds__(256) void GCNLarge_20761871909627_kernel(int* __restrict__ buf, int n) {
    int i = blockIdx.x * 256 + threadIdx.x;
    if (i < n) buf[i] = 0;
}

// ---------- runtime layout detection (wave-parallel) ----------

__global__ void detect_kernel(const int* __restrict__ ei, const unsigned int* __restrict__ xw,
                              int* __restrict__ flags) {
    int lane = threadIdx.x & 63;
    int any = 0;
    for (int k = lane; k < 128; k += 64) any |= ei[2 * k + 1];
    int hits = 0;
    for (int k = lane; k < 256; k += 64) {
        unsigned e = (xw[k] >> 7) & 0xFF;
        hits += (e >= 100 && e <= 140) ? 1 : 0;
    }
#pragma unroll
    for (int o = 32; o > 0; o >>= 1) {
        any |= __shfl_down(any, o);
        hits += __shfl_down(hits, o);
    }
    if (lane == 0) {
        flags[0] = (any == 0) ? 1 : 0;
        flags[1] = (hits >= 128) ? 1 : 0;
    }
}

__device__ __forceinline__ int edge_src(const int* ei, int e, int m) {
    return m ? ei[2 * (size_t)e] : ei[e];
}
__device__ __forceinline__ int edge_dst(const int* ei, int e, int m) {
    return m ? ei[2 * (size_t)NE + 2 * (size_t)e] : ei[(size_t)NE + e];
}

// ---------- degree / CSR build ----------

__global__ __launch_bounds__(256) void count_kernel(const int* __restrict__ ei,
                                                    const int* __restrict__ flags,
                                                    int* __restrict__ cnt) {
    int e = blockIdx.x * 256 + threadIdx.x;
    if (e < NE) {
        int d = edge_dst(ei, e, flags[0]);
        if ((unsigned)d < NN) atomicAdd(&cnt[d], 1);
    }
}

__global__ __launch_bounds__(256) void dis_kernel(const int* __restrict__ cnt,
                                                  float* __restrict__ dis) {
    int i = blockIdx.x * 256 + threadIdx.x;
    if (i < NNP) {
        int c = (i < NN) ? cnt[i] : 0;
        if (c < 0) c = 0;
        dis[i] = rsqrtf((float)(c + 1));
    }
}

__global__ __launch_bounds__(1024) void scan1_kernel(const int* __restrict__ cnt,
                                                     int* __restrict__ off,
                                                     int* __restrict__ bsum) {
    __shared__ int s[1024];
    int i = blockIdx.x * 1024 + threadIdx.x;
    int v = (i < NN) ? cnt[i] : 0;
    s[threadIdx.x] = v;
    __syncthreads();
    for (int d = 1; d < 1024; d <<= 1) {
        int tv = (threadIdx.x >= d) ? s[threadIdx.x - d] : 0;
        __syncthreads();
        s[threadIdx.x] += tv;
        __syncthreads();
    }
    if (i < NN) off[i] = s[threadIdx.x] - v;
    if (threadIdx.x == 1023) bsum[blockIdx.x] = s[1023];
}

__global__ void scan2_kernel(int* __restrict__ bsum, int nb) {
    if (threadIdx.x == 0 && blockIdx.x == 0) {
        int acc = 0;
        for (int b = 0; b < nb; b++) { int v = bsum[b]; bsum[b] = acc; acc += v; }
    }
}

__global__ __launch_bounds__(1024) void scan3_kernel(int* __restrict__ off,
                                                     const int* __restrict__ bsum,
                                                     int* __restrict__ cursor) {
    int i = blockIdx.x * 1024 + threadIdx.x;
    if (i < NN) { int o = off[i] + bsum[blockIdx.x]; off[i] = o; cursor[i] = o; }
    if (i == 0) off[NN] = NE;
}

__global__ __launch_bounds__(256) void place_kernel(const int* __restrict__ ei,
                                                    const int* __restrict__ flags,
                                                    int* __restrict__ cursor,
                                                    int* __restrict__ csr) {
    int e = blockIdx.x * 256 + threadIdx.x;
    if (e < NE) {
        int m = flags[0];
        int s = edge_src(ei, e, m);
        int d = edge_dst(ei, e, m);
        if ((unsigned)s < NN && (unsigned)d < NN) {
            int slot = atomicAdd(&cursor[d], 1);
            if ((unsigned)slot < NE) csr[slot] = s;
        }
    }
}

// ---------- W -> W^T (bf16) in global: Wt[n][k] = W[k][n], zero-padded to Kpad ----------

__global__ __launch_bounds__(256) void wt_kernel(const void* __restrict__ W,
                                                 const int* __restrict__ flags,
                                                 unsigned short* __restrict__ Wt,
                                                 int K, int Kpad, int total) {
    int idx = blockIdx.x * 256 + threadIdx.x;
    if (idx >= total) return;
    int n = idx / Kpad, k = idx - n * Kpad;
    unsigned short v = 0;
    if (k < K) {
        if (flags[1]) v = ((const unsigned short*)W)[(size_t)k * HID + n];
        else          v = f2bf(((const float*)W)[(size_t)k * HID + n]);
    }
    Wt[idx] = v;
}

// ---------- layers 2-4: barrier-free register GEMM ----------
// bf16 [NNP,128] @ Wt[128][128] -> bf16, row-scaled by dis. B frags in regs (loaded once
// per block), A frags direct from global (16 coalesced 64B lines per load instr), 4 row
// tiles per block with ping-pong A prefetch. No LDS, no __syncthreads.

__global__ __launch_bounds__(256) void gemmWr_kernel(const unsigned short* __restrict__ A,
                                                     const unsigned short* __restrict__ Wt,
                                                     const float* __restrict__ dis,
                                                     unsigned short* __restrict__ out) {
    int tid = threadIdx.x;
    int w = tid >> 6, lane = tid & 63;
    int m = lane & 15, quad = lane >> 4;
    int mbase = (w >> 1) * 32, nbase = (w & 1) * 64;
    short8 b[4][4];
#pragma unroll
    for (int nt = 0; nt < 4; nt++)
#pragma unroll
        for (int kq = 0; kq < 4; kq++)
            b[nt][kq] = *(const short8*)(Wt + (size_t)(nbase + nt * 16 + m) * HID + kq * 32 + quad * 8);
    int t0 = blockIdx.x * 4;
    short8 aP[4][2], aQ[4][2];
    auto loadA = [&](int t, short8 a[4][2]) {
        const unsigned short* p0 = A + (size_t)(t * 64 + mbase + m) * HID + quad * 8;
        const unsigned short* p1 = p0 + (size_t)16 * HID;
#pragma unroll
        for (int kq = 0; kq < 4; kq++) {
            a[kq][0] = *(const short8*)(p0 + kq * 32);
            a[kq][1] = *(const short8*)(p1 + kq * 32);
        }
    };
    loadA(t0, aP);
#pragma unroll
    for (int tt = 0; tt < 4; tt++) {
        if (tt < 3) loadA(t0 + tt + 1, (tt & 1) ? aP : aQ);
        short8 (*ac)[2] = (tt & 1) ? aQ : aP;
        f32x4 acc[2][4] = {};
#pragma unroll
        for (int kq = 0; kq < 4; kq++)
#pragma unroll
            for (int nt = 0; nt < 4; nt++) {
                acc[0][nt] = __builtin_amdgcn_mfma_f32_16x16x32_bf16(ac[kq][0], b[nt][kq], acc[0][nt], 0, 0, 0);
                acc[1][nt] = __builtin_amdgcn_mfma_f32_16x16x32_bf16(ac[kq][1], b[nt][kq], acc[1][nt], 0, 0, 0);
            }
        int r0 = (t0 + tt) * 64;
#pragma unroll
        for (int mt = 0; mt < 2; mt++) {
            int rb = r0 + mbase + mt * 16 + quad * 4;
#pragma unroll
            for (int reg = 0; reg < 4; reg++) {
                float d = dis[rb + reg];
#pragma unroll
                for (int nt = 0; nt < 4; nt++)
                    out[(size_t)(rb + reg) * HID + nbase + nt * 16 + m] = f2bf(acc[mt][nt][reg] * d);
            }
        }
    }
}

// ---------- layer 1: LDS-staged-B register GEMM, x [NN,500] @ Wt1[128][512] ----------
// Per kc (K-slice of 128): cooperatively stage B slice (128 cols x 128 k = 32 KB) into
// LDS with XOR-swizzled chunk placement (16B granule; row stride 256B would otherwise be
// a 16-way bank conflict on ds_read_b128). A frags (16 x 8B loads/wave) issue as an
// independent batch that drains in the same vmcnt(0) as the staging loads at the
// barrier -> one shared HBM latency per kc instead of a serialized load-use chain
// (old version: VGPR-capped compiler sank B loads into MFMA uses; 3.4% MfmaUtil,
// 5% VALUBusy, 11% HBM -> pure latency serialization).

__global__ __launch_bounds__(256) void gemm1r_kernel(const void* __restrict__ Av,
                                                     const unsigned short* __restrict__ Wt1,
                                                     const float* __restrict__ dis,
                                                     const int* __restrict__ flags,
                                                     unsigned short* __restrict__ out) {
    __shared__ unsigned short Bs[128 * 128];   // 32 KB, slot (n, c) holds Wt1 chunk c^(n&15)
    int tid = threadIdx.x;
    int bf = flags[1];
    int w = tid >> 6, lane = tid & 63;
    int m = lane & 15, quad = lane >> 4;
    int mbase = (w >> 1) * 32, nbase = (w & 1) * 64;
    int r0 = blockIdx.x * 64;
    int row0 = r0 + mbase + m;       int rc0 = (row0 < NN) ? row0 : NN - 1;
    int row1 = r0 + mbase + 16 + m;  int rc1 = (row1 < NN) ? row1 : NN - 1;
    f32x4 acc[2][4] = {};
#pragma unroll 1
    for (int kc = 0; kc < 4; kc++) {
        // --- stage B slice: 2048 16B chunks, 8 per thread, swizzled source chunk ---
#pragma unroll
        for (int it = 0; it < 8; it++) {
            int chunk = it * 256 + tid;
            int n = chunk >> 4, c = chunk & 15;
            int sc = c ^ (n & 15);
            *(short8*)(&Bs[n * 128 + c * 8]) =
                *(const short8*)(Wt1 + (size_t)n * 512 + kc * 128 + sc * 8);
        }
        // --- A fragments for this kc: independent batch, overlaps staging drain ---
        short8 a[4][2];
#pragma unroll
        for (int kq = 0; kq < 4; kq++) {
            int k_off = kc * 128 + kq * 32 + quad * 8;
            ushort4 z = make_ushort4(0, 0, 0, 0);
#pragma unroll
            for (int mt = 0; mt < 2; mt++) {
                int rr = mt ? rc1 : rc0;
                ushort4 lo = z, hi = z;
                if (bf) {
                    const unsigned short* xp = (const unsigned short*)Av + (size_t)rr * FIN + k_off;
                    if (k_off + 4 <= FIN) lo = *(const ushort4*)xp;
                    if (k_off + 8 <= FIN) hi = *(const ushort4*)(xp + 4);
                } else {
                    const float* xp = (const float*)Av + (size_t)rr * FIN + k_off;
                    if (k_off + 4 <= FIN) { float4 f = *(const float4*)xp;
                        lo = make_ushort4(f2bf(f.x), f2bf(f.y), f2bf(f.z), f2bf(f.w)); }
                    if (k_off + 8 <= FIN) { float4 f = *(const float4*)(xp + 4);
                        hi = make_ushort4(f2bf(f.x), f2bf(f.y), f2bf(f.z), f2bf(f.w)); }
                }
                a[kq][mt] = short8{(short)lo.x, (short)lo.y, (short)lo.z, (short)lo.w,
                                   (short)hi.x, (short)hi.y, (short)hi.z, (short)hi.w};
            }
        }
        __syncthreads();   // staging writes + A batch drain together
        // --- MFMA over the slice, B frags via swizzled ds_read_b128 ---
#pragma unroll
        for (int kq = 0; kq < 4; kq++)
#pragma unroll
            for (int nt = 0; nt < 4; nt++) {
                int n = nbase + nt * 16 + m;
                short8 b = *(const short8*)(&Bs[n * 128 + (((kq * 4 + quad) ^ (n & 15)) * 8)]);
                acc[0][nt] = __builtin_amdgcn_mfma_f32_16x16x32_bf16(a[kq][0], b, acc[0][nt], 0, 0, 0);
                acc[1][nt] = __builtin_amdgcn_mfma_f32_16x16x32_bf16(a[kq][1], b, acc[1][nt], 0, 0, 0);
            }
        __syncthreads();   // protect Bs from next kc's staging
    }
#pragma unroll
    for (int mt = 0; mt < 2; mt++) {
        int rb = r0 + mbase + mt * 16 + quad * 4;
#pragma unroll
        for (int reg = 0; reg < 4; reg++) {
            int row = rb + reg;
            if (row < NN) {
                float d = dis[row];
#pragma unroll
                for (int nt = 0; nt < 4; nt++)
                    out[(size_t)row * HID + nbase + nt * 16 + m] = f2bf(acc[mt][nt][reg] * d);
            }
        }
    }
}

// ---------- aggregation over bf16 features, f32 accumulate, 8x unrolled ----------

__global__ __launch_bounds__(256) void aggb_kernel(const unsigned short* __restrict__ tin,
                                                   const int* __restrict__ off,
                                                   const int* __restrict__ csr,
                                                   const float* __restrict__ dis,
                                                   const void* __restrict__ bias,
                                                   const int* __restrict__ flags,
                                                   unsigned short* __restrict__ hout,
                                                   int relu, int scale_src) {
    int node = blockIdx.x * 4 + (threadIdx.x >> 6);   // one wave per node
    int lane = threadIdx.x & 63;                      // 2 features per lane (1 dword)
    float di = dis[node];
    unsigned int sv = *(const unsigned int*)(tin + (size_t)node * HID + lane * 2);
    float acc0 = scale_src ? di * lo16(sv) : lo16(sv);
    float acc1 = scale_src ? di * hi16(sv) : hi16(sv);
    int e0 = off[node], e1 = off[node + 1];
    if (e0 < 0) e0 = 0;
    if (e1 > NE) e1 = NE;
    int e = e0;
    if (!scale_src) {
        for (; e + 8 <= e1; e += 8) {
            int i0 = csr[e],     i1 = csr[e + 1], i2 = csr[e + 2], i3 = csr[e + 3];
            int i4 = csr[e + 4], i5 = csr[e + 5], i6 = csr[e + 6], i7 = csr[e + 7];
            unsigned int v0 = *(const unsigned int*)(tin + (size_t)i0 * HID + lane * 2);
            unsigned int v1 = *(const unsigned int*)(tin + (size_t)i1 * HID + lane * 2);
            unsigned int v2 = *(const unsigned int*)(tin + (size_t)i2 * HID + lane * 2);
            unsigned int v3 = *(const unsigned int*)(tin + (size_t)i3 * HID + lane * 2);
            unsigned int v4 = *(const unsigned int*)(tin + (size_t)i4 * HID + lane * 2);
            unsigned int v5 = *(const unsigned int*)(tin + (size_t)i5 * HID + lane * 2);
            unsigned int v6 = *(const unsigned int*)(tin + (size_t)i6 * HID + lane * 2);
            unsigned int v7 = *(const unsigned int*)(tin + (size_t)i7 * HID + lane * 2);
            acc0 += lo16(v0); acc1 += hi16(v0); acc0 += lo16(v1); acc1 += hi16(v1);
            acc0 += lo16(v2); acc1 += hi16(v2); acc0 += lo16(v3); acc1 += hi16(v3);
            acc0 += lo16(v4); acc1 += hi16(v4); acc0 += lo16(v5); acc1 += hi16(v5);
            acc0 += lo16(v6); acc1 += hi16(v6); acc0 += lo16(v7); acc1 += hi16(v7);
        }
        for (; e + 4 <= e1; e += 4) {
            int i0 = csr[e], i1 = csr[e + 1], i2 = csr[e + 2], i3 = csr[e + 3];
            unsigned int v0 = *(const unsigned int*)(tin + (size_t)i0 * HID + lane * 2);
            unsigned int v1 = *(const unsigned int*)(tin + (size_t)i1 * HID + lane * 2);
            unsigned int v2 = *(const unsigned int*)(tin + (size_t)i2 * HID + lane * 2);
            unsigned int v3 = *(const unsigned int*)(tin + (size_t)i3 * HID + lane * 2);
            acc0 += lo16(v0); acc1 += hi16(v0); acc0 += lo16(v1); acc1 += hi16(v1);
            acc0 += lo16(v2); acc1 += hi16(v2); acc0 += lo16(v3); acc1 += hi16(v3);
        }
        for (; e < e1; e++) {
            int s = csr[e];
            unsigned int v = *(const unsigned int*)(tin + (size_t)s * HID + lane * 2);
            acc0 += lo16(v); acc1 += hi16(v);
        }
    } else {
        for (; e + 8 <= e1; e += 8) {
            int i0 = csr[e],     i1 = csr[e + 1], i2 = csr[e + 2], i3 = csr[e + 3];
            int i4 = csr[e + 4], i5 = csr[e + 5], i6 = csr[e + 6], i7 = csr[e + 7];
            unsigned int v0 = *(const unsigned int*)(tin + (size_t)i0 * HID + lane * 2);
            unsigned int v1 = *(const unsigned int*)(tin + (size_t)i1 * HID + lane * 2);
            unsigned int v2 = *(const unsigned int*)(tin + (size_t)i2 * HID + lane * 2);
            unsigned int v3 = *(const unsigned int*)(tin + (size_t)i3 * HID + lane * 2);
            unsigned int v4 = *(const unsigned int*)(tin + (size_t)i4 * HID + lane * 2);
            unsigned int v5 = *(const unsigned int*)(tin + (size_t)i5 * HID + lane * 2);
            unsigned int v6 = *(const unsigned int*)(tin + (size_t)i6 * HID + lane * 2);
            unsigned int v7 = *(const unsigned int*)(tin + (size_t)i7 * HID + lane * 2);
            float m0 = dis[i0], m1 = dis[i1], m2 = dis[i2], m3 = dis[i3];
            float m4 = dis[i4], m5 = dis[i5], m6 = dis[i6], m7 = dis[i7];
            acc0 += m0 * lo16(v0); acc1 += m0 * hi16(v0);
            acc0 += m1 * lo16(v1); acc1 += m1 * hi16(v1);
            acc0 += m2 * lo16(v2); acc1 += m2 * hi16(v2);
            acc0 += m3 * lo16(v3); acc1 += m3 * hi16(v3);
            acc0 += m4 * lo16(v4); acc1 += m4 * hi16(v4);
            acc0 += m5 * lo16(v5); acc1 += m5 * hi16(v5);
            acc0 += m6 * lo16(v6); acc1 += m6 * hi16(v6);
            acc0 += m7 * lo16(v7); acc1 += m7 * hi16(v7);
        }
        for (; e < e1; e++) {
            int s = csr[e];
            unsigned int v = *(const unsigned int*)(tin + (size_t)s * HID + lane * 2);
            float mm = dis[s];
            acc0 += mm * lo16(v); acc1 += mm * hi16(v);
        }
    }
    float o0 = di * acc0, o1 = di * acc1;
    if (bias) {
        if (flags[1]) { o0 += bf2f(((const unsigned short*)bias)[lane * 2]);
                        o1 += bf2f(((const unsigned short*)bias)[lane * 2 + 1]); }
        else          { o0 += ((const float*)bias)[lane * 2];
                        o1 += ((const float*)bias)[lane * 2 + 1]; }
    }
    if (relu) { o0 = fmaxf(o0, 0.f); o1 = fmaxf(o1, 0.f); }
    unsigned int pk = ((unsigned int)f2bf(o1) << 16) | (unsigned int)f2bf(o0);
    *(unsigned int*)(hout + (size_t)node * HID + lane * 2) = pk;
}

// ---------- layer 5: bf16 [NN,128] @ W5 [128,3] + b5 -> out (dtype per flags[1]) ----------

__global__ __launch_bounds__(256) void gemm5_kernel(const unsigned short* __restrict__ A,
                                                    const void* __restrict__ W5v,
                                                    const void* __restrict__ b5v,
                                                    const int* __restrict__ flags,
                                                    void* __restrict__ outv) {
    __shared__ float Ws[384];
    __shared__ float bs[3];
    int tid = threadIdx.x;
    int bf = flags[1];
    for (int idx = tid; idx < 384; idx += 256)
        Ws[idx] = bf ? bf2f(((const unsigned short*)W5v)[idx]) : ((const float*)W5v)[idx];
    if (tid < 3)
        bs[tid] = bf ? bf2f(((const unsigned short*)b5v)[tid]) : ((const float*)b5v)[tid];
    __syncthreads();
    int lane = tid & 63;
    int row = blockIdx.x * 4 + (tid >> 6);
    float a0 = bf2f(A[(size_t)row * HID + lane]);
    float a1 = bf2f(A[(size_t)row * HID + 64 + lane]);
    float c0 = a0 * Ws[lane * 3 + 0] + a1 * Ws[(lane + 64) * 3 + 0];
    float c1 = a0 * Ws[lane * 3 + 1] + a1 * Ws[(lane + 64) * 3 + 1];
    float c2 = a0 * Ws[lane * 3 + 2] + a1 * Ws[(lane + 64) * 3 + 2];
#pragma unroll
    for (int o = 32; o > 0; o >>= 1) {
        c0 += __shfl_down(c0, o);
        c1 += __shfl_down(c1, o);
        c2 += __shfl_down(c2, o);
    }
    if (lane == 0) {
        c0 += bs[0]; c1 += bs[1]; c2 += bs[2];
        if (bf) {
            unsigned short* out = (unsigned short*)outv;
            out[(size_t)row * 3 + 0] = f2bf(c0);
            out[(size_t)row * 3 + 1] = f2bf(c1);
            out[(size_t)row * 3 + 2] = f2bf(c2);
        } else {
            float* out = (float*)outv;
            out[(size_t)row * 3 + 0] = c0;
            out[(size_t)row * 3 + 1] = c1;
            out[(size_t)row * 3 + 2] = c2;
        }
    }
}

extern "C" void kernel_launch(void* const* d_in, const int* in_sizes, int n_in,
                              void* d_out, int out_size, void* d_ws, size_t ws_size,
                              hipStream_t stream) {
    const void* x = nullptr; const int* ei = nullptr;
    const void* W1 = nullptr; const void* W5 = nullptr; const void* b5 = nullptr;
    const void* Wmid[3] = {nullptr, nullptr, nullptr};
    const void* bvec[4] = {nullptr, nullptr, nullptr, nullptr};
    int nw = 0, nb = 0;
    for (int i = 0; i < n_in; i++) {
        int s = in_sizes[i];
        if      (s == 50000000) x = d_in[i];
        else if (s == 3200000)  ei = (const int*)d_in[i];
        else if (s == 64000)    W1 = d_in[i];
        else if (s == 16384)  { if (nw < 3) Wmid[nw++] = d_in[i]; }
        else if (s == 384)      W5 = d_in[i];
        else if (s == 128)    { if (nb < 4) bvec[nb++] = d_in[i]; }
        else if (s == 3)        b5 = d_in[i];
    }
    if (!x || !ei || !W1 || !W5 || !b5 || nw < 3 || nb < 4) return;

    char* p = (char*)d_ws;
    auto alloc = [&](size_t bytes) { char* q = p; p += (bytes + 255) & ~(size_t)255; return (void*)q; };
    int*   flags = (int*)alloc(256);
    float* dis   = (float*)alloc((size_t)NNP * 4);
    int*   cnt   = (int*)alloc((size_t)NN * 4);
    int*   off   = (int*)alloc((size_t)(NN + 1) * 4);
    int*   cur   = (int*)alloc((size_t)NN * 4);
    int*   bsum  = (int*)alloc(128 * 4);
    int*   csr   = (int*)alloc((size_t)NE * 4);
    unsigned short* Wt1 = (unsigned short*)alloc((size_t)128 * 512 * 2);
    unsigned short* Wt2 = (unsigned short*)alloc((size_t)128 * 128 * 2);
    unsigned short* Wt3 = (unsigned short*)alloc((size_t)128 * 128 * 2);
    unsigned short* Wt4 = (unsigned short*)alloc((size_t)128 * 128 * 2);
    unsigned short* T   = (unsigned short*)alloc((size_t)NNP * HID * 2);
    unsigned short* H   = (unsigned short*)alloc((size_t)NNP * HID * 2);

    // graph build + weight transposes
    GCNLarge_20761871909627_kernel<<<(NN + 255) / 256, 256, 0, stream>>>(cnt, NN);
    detect_kernel<<<1, 64, 0, stream>>>(ei, (const unsigned int*)x, flags);
    wt_kernel<<<256, 256, 0, stream>>>(W1, flags, Wt1, FIN, 512, 128 * 512);
    wt_kernel<<<64, 256, 0, stream>>>(Wmid[0], flags, Wt2, HID, 128, 128 * 128);
    wt_kernel<<<64, 256, 0, stream>>>(Wmid[1], flags, Wt3, HID, 128, 128 * 128);
    wt_kernel<<<64, 256, 0, stream>>>(Wmid[2], flags, Wt4, HID, 128, 128 * 128);
    count_kernel<<<(NE + 255) / 256, 256, 0, stream>>>(ei, flags, cnt);
    dis_kernel<<<(NNP + 255) / 256, 256, 0, stream>>>(cnt, dis);
    scan1_kernel<<<98, 1024, 0, stream>>>(cnt, off, bsum);
    scan2_kernel<<<1, 64, 0, stream>>>(bsum, 98);
    scan3_kernel<<<98, 1024, 0, stream>>>(off, bsum, cur);
    place_kernel<<<(NE + 255) / 256, 256, 0, stream>>>(ei, flags, cur, csr);

    // layer 1
    gemm1r_kernel<<<NNP / 64, 256, 0, stream>>>(x, Wt1, dis, flags, T);
    aggb_kernel<<<NN / 4, 256, 0, stream>>>(T, off, csr, dis, bvec[0], flags, H, 1, 0);
    // layers 2-4 (T/H ping-pong), 391 blocks x 4 tiles x 64 rows = NNP
    gemmWr_kernel<<<NNP / 256, 256, 0, stream>>>(H, Wt2, dis, T);
    aggb_kernel<<<NN / 4, 256, 0, stream>>>(T, off, csr, dis, bvec[1], flags, H, 1, 0);
    gemmWr_kernel<<<NNP / 256, 256, 0, stream>>>(H, Wt3, dis, T);
    aggb_kernel<<<NN / 4, 256, 0, stream>>>(T, off, csr, dis, bvec[2], flags, H, 1, 0);
    gemmWr_kernel<<<NNP / 256, 256, 0, stream>>>(H, Wt4, dis, T);
    aggb_kernel<<<NN / 4, 256, 0, stream>>>(T, off, csr, dis, bvec[3], flags, H, 1, 0);
    // layer 5: aggregate first (linearity), then small GEMM
    aggb_kernel<<<NN / 4, 256, 0, stream>>>(H, off, csr, dis, nullptr, flags, T, 0, 1);
    gemm5_kernel<<<NN / 4, 256, 0, stream>>>(T, W5, b5, flags, d_out);
}

// Round 2
// 992.529 us; speedup vs baseline: 1.0128x; 1.0094x over previous
//
#include <hip/hip_runtime.h>
#include <hip/hip_bf16.h>

#define NN 100000
#define NNP 100096   // padded rows: multiple of 256
#define NE 1600000
#define FIN 500
#define HID 128

typedef __attribute__((ext_vector_type(8))) short short8;   // 8 bf16 = 4 VGPRs (MFMA A/B frag)
typedef __attribute__((ext_vector_type(4))) float f32x4;    // MFMA C/D frag

__device__ __forceinline__ float bf2f(unsigned short u) {
    return __uint_as_float(((unsigned int)u) << 16);
}
__device__ __forceinline__ unsigned short f2bf(float f) {
    __hip_bfloat16 h = __float2bfloat16(f);
    return *(unsigned short*)&h;
}
__device__ __forceinline__ float lo16(unsigned int v) { return __uint_as_float(v << 16); }
__device__ __forceinline__ float hi16(unsigned int v) { return __uint_as_float(v & 0xffff0000u); }

// ---------- template-named kernel (serves as cnt zeroing) ----------

__global__ __launch_bounds__(256) void GCNLarge_20761871909627_kernel(int* __restrict__ buf, int n) {
    int i = blockIdx.x * 256 + threadIdx.x;
    if (i < n) buf[i] = 0;
}

// ---------- runtime layout detection (wave-parallel) ----------

__global__ void detect_kernel(const int* __restrict__ ei, const unsigned int* __restrict__ xw,
                              int* __restrict__ flags) {
    int lane = threadIdx.x & 63;
    int any = 0;
    for (int k = lane; k < 128; k += 64) any |= ei[2 * k + 1];
    int hits = 0;
    for (int k = lane; k < 256; k += 64) {
        unsigned e = (xw[k] >> 7) & 0xFF;
        hits += (e >= 100 && e <= 140) ? 1 : 0;
    }
#pragma unroll
    for (int o = 32; o > 0; o >>= 1) {
        any |= __shfl_down(any, o);
        hits += __shfl_down(hits, o);
    }
    if (lane == 0) {
        flags[0] = (any == 0) ? 1 : 0;
        flags[1] = (hits >= 128) ? 1 : 0;
    }
}

__device__ __forceinline__ int edge_src(const int* ei, int e, int m) {
    return m ? ei[2 * (size_t)e] : ei[e];
}
__device__ __forceinline__ int edge_dst(const int* ei, int e, int m) {
    return m ? ei[2 * (size_t)NE + 2 * (size_t)e] : ei[(size_t)NE + e];
}

// ---------- degree / CSR build ----------

__global__ __launch_bounds__(256) void count_kernel(const int* __restrict__ ei,
                                                    const int* __restrict__ flags,
                                                    int* __restrict__ cnt) {
    int e = blockIdx.x * 256 + threadIdx.x;
    if (e < NE) {
        int d = edge_dst(ei, e, flags[0]);
        if ((unsigned)d < NN) atomicAdd(&cnt[d], 1);
    }
}

__global__ __launch_bounds__(256) void dis_kernel(const int* __restrict__ cnt,
                                                  float* __restrict__ dis) {
    int i = blockIdx.x * 256 + threadIdx.x;
    if (i < NNP) {
        int c = (i < NN) ? cnt[i] : 0;
        if (c < 0) c = 0;
        dis[i] = rsqrtf((float)(c + 1));
    }
}

__global__ __launch_bounds__(1024) void scan1_kernel(const int* __restrict__ cnt,
                                                     int* __restrict__ off,
                                                     int* __restrict__ bsum) {
    __shared__ int s[1024];
    int i = blockIdx.x * 1024 + threadIdx.x;
    int v = (i < NN) ? cnt[i] : 0;
    s[threadIdx.x] = v;
    __syncthreads();
    for (int d = 1; d < 1024; d <<= 1) {
        int tv = (threadIdx.x >= d) ? s[threadIdx.x - d] : 0;
        __syncthreads();
        s[threadIdx.x] += tv;
        __syncthreads();
    }
    if (i < NN) off[i] = s[threadIdx.x] - v;
    if (threadIdx.x == 1023) bsum[blockIdx.x] = s[1023];
}

__global__ void scan2_kernel(int* __restrict__ bsum, int nb) {
    if (threadIdx.x == 0 && blockIdx.x == 0) {
        int acc = 0;
        for (int b = 0; b < nb; b++) { int v = bsum[b]; bsum[b] = acc; acc += v; }
    }
}

__global__ __launch_bounds__(1024) void scan3_kernel(int* __restrict__ off,
                                                     const int* __restrict__ bsum,
                                                     int* __restrict__ cursor) {
    int i = blockIdx.x * 1024 + threadIdx.x;
    if (i < NN) { int o = off[i] + bsum[blockIdx.x]; off[i] = o; cursor[i] = o; }
    if (i == 0) off[NN] = NE;
}

__global__ __launch_bounds__(256) void place_kernel(const int* __restrict__ ei,
                                                    const int* __restrict__ flags,
                                                    int* __restrict__ cursor,
                                                    int* __restrict__ csr) {
    int e = blockIdx.x * 256 + threadIdx.x;
    if (e < NE) {
        int m = flags[0];
        int s = edge_src(ei, e, m);
        int d = edge_dst(ei, e, m);
        if ((unsigned)s < NN && (unsigned)d < NN) {
            int slot = atomicAdd(&cursor[d], 1);
            if ((unsigned)slot < NE) csr[slot] = s;
        }
    }
}

// ---------- W -> W^T (bf16) in global: Wt[n][k] = W[k][n], zero-padded to Kpad ----------

__global__ __launch_bounds__(256) void wt_kernel(const void* __restrict__ W,
                                                 const int* __restrict__ flags,
                                                 unsigned short* __restrict__ Wt,
                                                 int K, int Kpad, int total) {
    int idx = blockIdx.x * 256 + threadIdx.x;
    if (idx >= total) return;
    int n = idx / Kpad, k = idx - n * Kpad;
    unsigned short v = 0;
    if (k < K) {
        if (flags[1]) v = ((const unsigned short*)W)[(size_t)k * HID + n];
        else          v = f2bf(((const float*)W)[(size_t)k * HID + n]);
    }
    Wt[idx] = v;
}

// ---------- layers 2-4: barrier-free register GEMM ----------
// bf16 [NNP,128] @ Wt[128][128] -> bf16, row-scaled by dis. B frags in regs (loaded once
// per block), A frags direct from global (16 coalesced 64B lines per load instr), 4 row
// tiles per block with ping-pong A prefetch. No LDS, no __syncthreads.

__global__ __launch_bounds__(256) void gemmWr_kernel(const unsigned short* __restrict__ A,
                                                     const unsigned short* __restrict__ Wt,
                                                     const float* __restrict__ dis,
                                                     unsigned short* __restrict__ out) {
    int tid = threadIdx.x;
    int w = tid >> 6, lane = tid & 63;
    int m = lane & 15, quad = lane >> 4;
    int mbase = (w >> 1) * 32, nbase = (w & 1) * 64;
    short8 b[4][4];
#pragma unroll
    for (int nt = 0; nt < 4; nt++)
#pragma unroll
        for (int kq = 0; kq < 4; kq++)
            b[nt][kq] = *(const short8*)(Wt + (size_t)(nbase + nt * 16 + m) * HID + kq * 32 + quad * 8);
    int t0 = blockIdx.x * 4;
    short8 aP[4][2], aQ[4][2];
    auto loadA = [&](int t, short8 a[4][2]) {
        const unsigned short* p0 = A + (size_t)(t * 64 + mbase + m) * HID + quad * 8;
        const unsigned short* p1 = p0 + (size_t)16 * HID;
#pragma unroll
        for (int kq = 0; kq < 4; kq++) {
            a[kq][0] = *(const short8*)(p0 + kq * 32);
            a[kq][1] = *(const short8*)(p1 + kq * 32);
        }
    };
    loadA(t0, aP);
#pragma unroll
    for (int tt = 0; tt < 4; tt++) {
        if (tt < 3) loadA(t0 + tt + 1, (tt & 1) ? aP : aQ);
        short8 (*ac)[2] = (tt & 1) ? aQ : aP;
        f32x4 acc[2][4] = {};
#pragma unroll
        for (int kq = 0; kq < 4; kq++)
#pragma unroll
            for (int nt = 0; nt < 4; nt++) {
                acc[0][nt] = __builtin_amdgcn_mfma_f32_16x16x32_bf16(ac[kq][0], b[nt][kq], acc[0][nt], 0, 0, 0);
                acc[1][nt] = __builtin_amdgcn_mfma_f32_16x16x32_bf16(ac[kq][1], b[nt][kq], acc[1][nt], 0, 0, 0);
            }
        int r0 = (t0 + tt) * 64;
#pragma unroll
        for (int mt = 0; mt < 2; mt++) {
            int rb = r0 + mbase + mt * 16 + quad * 4;
#pragma unroll
            for (int reg = 0; reg < 4; reg++) {
                float d = dis[rb + reg];
#pragma unroll
                for (int nt = 0; nt < 4; nt++)
                    out[(size_t)(rb + reg) * HID + nbase + nt * 16 + m] = f2bf(acc[mt][nt][reg] * d);
            }
        }
    }
}

// ---------- layer 1: LDS-staged A+B GEMM, x [NN,500] @ Wt1[128][512] ----------
// Round-0 post-mortem: B-side LDS staging changed nothing (149us identical) -> the
// bottleneck is the A-load pattern: per-fragment loads had 16 lanes reading 16 rows at
// 2000B stride = ~16 scattered cache lines per VMEM instr, with VGPR-capped MLP.
// Fix: cooperative A staging with LANE-CONTIGUOUS loads (per wave-instr: 2 rows x 512B
// fully-used lines), fp32->bf16 convert in the staging pass, XOR-swizzled As so the
// fragment ds_read_b128 (16 rows @ 256B stride) is bank-conflict-free. Per kc all
// 16 global loads/thread (8 A + 8 B) issue as one independent batch draining in a
// single vmcnt at the barrier.

__global__ __launch_bounds__(256) void gemm1s_kernel(const void* __restrict__ Av,
                                                     const unsigned short* __restrict__ Wt1,
                                                     const float* __restrict__ dis,
                                                     const int* __restrict__ flags,
                                                     unsigned short* __restrict__ out) {
    __shared__ unsigned short As[64 * 128];    // 16 KB, slot (row, c) holds chunk c^(row&15)
    __shared__ unsigned short Bs[128 * 128];   // 32 KB, slot (n, c) holds chunk c^(n&15)
    int tid = threadIdx.x;
    int bf = flags[1];
    int w = tid >> 6, lane = tid & 63;
    int m = lane & 15, quad = lane >> 4;
    int mbase = (w >> 1) * 32, nbase = (w & 1) * 64;
    int r0 = blockIdx.x * 64;
    // A staging coords: thread handles 4 cols of one row per iteration, lane-contiguous
    int srow = tid >> 5;            // + i*8
    int scol = (tid & 31) * 4;      // float/bf16 column granule
    int schunk = scol >> 3;         // 16B chunk index (8 bf16)
    int shalf = (scol >> 2) & 1;    // which 8B half of the chunk
    f32x4 acc[2][4] = {};
#pragma unroll 1
    for (int kc = 0; kc < 4; kc++) {
        // --- stage B slice: 2048 16B chunks, 8 per thread, swizzled source chunk ---
#pragma unroll
        for (int it = 0; it < 8; it++) {
            int chunk = it * 256 + tid;
            int n = chunk >> 4, c = chunk & 15;
            int sc = c ^ (n & 15);
            *(short8*)(&Bs[n * 128 + c * 8]) =
                *(const short8*)(Wt1 + (size_t)n * 512 + kc * 128 + sc * 8);
        }
        // --- stage A slice: 64 rows x 128 cols, coalesced (2 rows x 512B per instr) ---
#pragma unroll
        for (int i = 0; i < 8; i++) {
            int row = i * 8 + srow;
            int grow = r0 + row;
            int gr = (grow < NN) ? grow : NN - 1;
            int gcol = kc * 128 + scol;
            ushort4 pk = make_ushort4(0, 0, 0, 0);
            if (gcol + 4 <= FIN) {
                if (bf) {
                    pk = *(const ushort4*)((const unsigned short*)Av + (size_t)gr * FIN + gcol);
                } else {
                    float4 f = *(const float4*)((const float*)Av + (size_t)gr * FIN + gcol);
                    pk = make_ushort4(f2bf(f.x), f2bf(f.y), f2bf(f.z), f2bf(f.w));
                }
            }
            int pos = schunk ^ (row & 15);
            *(ushort4*)(&As[row * 128 + pos * 8 + shalf * 4]) = pk;
        }
        __syncthreads();   // all staging loads drain in one vmcnt here
        // --- MFMA over the slice, A/B frags via swizzled ds_read_b128 ---
#pragma unroll
        for (int kq = 0; kq < 4; kq++) {
            int g = kq * 4 + quad;
            int ar0 = mbase + m;
            int ar1 = mbase + 16 + m;
            short8 a0 = *(const short8*)(&As[ar0 * 128 + ((g ^ m) * 8)]);
            short8 a1 = *(const short8*)(&As[ar1 * 128 + ((g ^ m) * 8)]);
#pragma unroll
            for (int nt = 0; nt < 4; nt++) {
                int n = nbase + nt * 16 + m;
                short8 b = *(const short8*)(&Bs[n * 128 + ((g ^ (n & 15)) * 8)]);
                acc[0][nt] = __builtin_amdgcn_mfma_f32_16x16x32_bf16(a0, b, acc[0][nt], 0, 0, 0);
                acc[1][nt] = __builtin_amdgcn_mfma_f32_16x16x32_bf16(a1, b, acc[1][nt], 0, 0, 0);
            }
        }
        __syncthreads();   // protect As/Bs from next kc's staging
    }
#pragma unroll
    for (int mt = 0; mt < 2; mt++) {
        int rb = r0 + mbase + mt * 16 + quad * 4;
#pragma unroll
        for (int reg = 0; reg < 4; reg++) {
            int row = rb + reg;
            if (row < NN) {
                float d = dis[row];
#pragma unroll
                for (int nt = 0; nt < 4; nt++)
                    out[(size_t)row * HID + nbase + nt * 16 + m] = f2bf(acc[mt][nt][reg] * d);
            }
        }
    }
}

// ---------- aggregation over bf16 features, f32 accumulate, 8x unrolled ----------

__global__ __launch_bounds__(256) void aggb_kernel(const unsigned short* __restrict__ tin,
                                                   const int* __restrict__ off,
                                                   const int* __restrict__ csr,
                                                   const float* __restrict__ dis,
                                                   const void* __restrict__ bias,
                                                   const int* __restrict__ flags,
                                                   unsigned short* __restrict__ hout,
                                                   int relu, int scale_src) {
    int node = blockIdx.x * 4 + (threadIdx.x >> 6);   // one wave per node
    int lane = threadIdx.x & 63;                      // 2 features per lane (1 dword)
    float di = dis[node];
    unsigned int sv = *(const unsigned int*)(tin + (size_t)node * HID + lane * 2);
    float acc0 = scale_src ? di * lo16(sv) : lo16(sv);
    float acc1 = scale_src ? di * hi16(sv) : hi16(sv);
    int e0 = off[node], e1 = off[node + 1];
    if (e0 < 0) e0 = 0;
    if (e1 > NE) e1 = NE;
    int e = e0;
    if (!scale_src) {
        for (; e + 8 <= e1; e += 8) {
            int i0 = csr[e],     i1 = csr[e + 1], i2 = csr[e + 2], i3 = csr[e + 3];
            int i4 = csr[e + 4], i5 = csr[e + 5], i6 = csr[e + 6], i7 = csr[e + 7];
            unsigned int v0 = *(const unsigned int*)(tin + (size_t)i0 * HID + lane * 2);
            unsigned int v1 = *(const unsigned int*)(tin + (size_t)i1 * HID + lane * 2);
            unsigned int v2 = *(const unsigned int*)(tin + (size_t)i2 * HID + lane * 2);
            unsigned int v3 = *(const unsigned int*)(tin + (size_t)i3 * HID + lane * 2);
            unsigned int v4 = *(const unsigned int*)(tin + (size_t)i4 * HID + lane * 2);
            unsigned int v5 = *(const unsigned int*)(tin + (size_t)i5 * HID + lane * 2);
            unsigned int v6 = *(const unsigned int*)(tin + (size_t)i6 * HID + lane * 2);
            unsigned int v7 = *(const unsigned int*)(tin + (size_t)i7 * HID + lane * 2);
            acc0 += lo16(v0); acc1 += hi16(v0); acc0 += lo16(v1); acc1 += hi16(v1);
            acc0 += lo16(v2); acc1 += hi16(v2); acc0 += lo16(v3); acc1 += hi16(v3);
            acc0 += lo16(v4); acc1 += hi16(v4); acc0 += lo16(v5); acc1 += hi16(v5);
            acc0 += lo16(v6); acc1 += hi16(v6); acc0 += lo16(v7); acc1 += hi16(v7);
        }
        for (; e + 4 <= e1; e += 4) {
            int i0 = csr[e], i1 = csr[e + 1], i2 = csr[e + 2], i3 = csr[e + 3];
            unsigned int v0 = *(const unsigned int*)(tin + (size_t)i0 * HID + lane * 2);
            unsigned int v1 = *(const unsigned int*)(tin + (size_t)i1 * HID + lane * 2);
            unsigned int v2 = *(const unsigned int*)(tin + (size_t)i2 * HID + lane * 2);
            unsigned int v3 = *(const unsigned int*)(tin + (size_t)i3 * HID + lane * 2);
            acc0 += lo16(v0); acc1 += hi16(v0); acc0 += lo16(v1); acc1 += hi16(v1);
            acc0 += lo16(v2); acc1 += hi16(v2); acc0 += lo16(v3); acc1 += hi16(v3);
        }
        for (; e < e1; e++) {
            int s = csr[e];
            unsigned int v = *(const unsigned int*)(tin + (size_t)s * HID + lane * 2);
            acc0 += lo16(v); acc1 += hi16(v);
        }
    } else {
        for (; e + 8 <= e1; e += 8) {
            int i0 = csr[e],     i1 = csr[e + 1], i2 = csr[e + 2], i3 = csr[e + 3];
            int i4 = csr[e + 4], i5 = csr[e + 5], i6 = csr[e + 6], i7 = csr[e + 7];
            unsigned int v0 = *(const unsigned int*)(tin + (size_t)i0 * HID + lane * 2);
            unsigned int v1 = *(const unsigned int*)(tin + (size_t)i1 * HID + lane * 2);
            unsigned int v2 = *(const unsigned int*)(tin + (size_t)i2 * HID + lane * 2);
            unsigned int v3 = *(const unsigned int*)(tin + (size_t)i3 * HID + lane * 2);
            unsigned int v4 = *(const unsigned int*)(tin + (size_t)i4 * HID + lane * 2);
            unsigned int v5 = *(const unsigned int*)(tin + (size_t)i5 * HID + lane * 2);
            unsigned int v6 = *(const unsigned int*)(tin + (size_t)i6 * HID + lane * 2);
            unsigned int v7 = *(const unsigned int*)(tin + (size_t)i7 * HID + lane * 2);
            float m0 = dis[i0], m1 = dis[i1], m2 = dis[i2], m3 = dis[i3];
            float m4 = dis[i4], m5 = dis[i5], m6 = dis[i6], m7 = dis[i7];
            acc0 += m0 * lo16(v0); acc1 += m0 * hi16(v0);
            acc0 += m1 * lo16(v1); acc1 += m1 * hi16(v1);
            acc0 += m2 * lo16(v2); acc1 += m2 * hi16(v2);
            acc0 += m3 * lo16(v3); acc1 += m3 * hi16(v3);
            acc0 += m4 * lo16(v4); acc1 += m4 * hi16(v4);
            acc0 += m5 * lo16(v5); acc1 += m5 * hi16(v5);
            acc0 += m6 * lo16(v6); acc1 += m6 * hi16(v6);
            acc0 += m7 * lo16(v7); acc1 += m7 * hi16(v7);
        }
        for (; e < e1; e++) {
            int s = csr[e];
            unsigned int v = *(const unsigned int*)(tin + (size_t)s * HID + lane * 2);
            float mm = dis[s];
            acc0 += mm * lo16(v); acc1 += mm * hi16(v);
        }
    }
    float o0 = di * acc0, o1 = di * acc1;
    if (bias) {
        if (flags[1]) { o0 += bf2f(((const unsigned short*)bias)[lane * 2]);
                        o1 += bf2f(((const unsigned short*)bias)[lane * 2 + 1]); }
        else          { o0 += ((const float*)bias)[lane * 2];
                        o1 += ((const float*)bias)[lane * 2 + 1]; }
    }
    if (relu) { o0 = fmaxf(o0, 0.f); o1 = fmaxf(o1, 0.f); }
    unsigned int pk = ((unsigned int)f2bf(o1) << 16) | (unsigned int)f2bf(o0);
    *(unsigned int*)(hout + (size_t)node * HID + lane * 2) = pk;
}

// ---------- layer 5: bf16 [NN,128] @ W5 [128,3] + b5 -> out (dtype per flags[1]) ----------

__global__ __launch_bounds__(256) void gemm5_kernel(const unsigned short* __restrict__ A,
                                                    const void* __restrict__ W5v,
                                                    const void* __restrict__ b5v,
                                                    const int* __restrict__ flags,
                                                    void* __restrict__ outv) {
    __shared__ float Ws[384];
    __shared__ float bs[3];
    int tid = threadIdx.x;
    int bf = flags[1];
    for (int idx = tid; idx < 384; idx += 256)
        Ws[idx] = bf ? bf2f(((const unsigned short*)W5v)[idx]) : ((const float*)W5v)[idx];
    if (tid < 3)
        bs[tid] = bf ? bf2f(((const unsigned short*)b5v)[tid]) : ((const float*)b5v)[tid];
    __syncthreads();
    int lane = tid & 63;
    int row = blockIdx.x * 4 + (tid >> 6);
    float a0 = bf2f(A[(size_t)row * HID + lane]);
    float a1 = bf2f(A[(size_t)row * HID + 64 + lane]);
    float c0 = a0 * Ws[lane * 3 + 0] + a1 * Ws[(lane + 64) * 3 + 0];
    float c1 = a0 * Ws[lane * 3 + 1] + a1 * Ws[(lane + 64) * 3 + 1];
    float c2 = a0 * Ws[lane * 3 + 2] + a1 * Ws[(lane + 64) * 3 + 2];
#pragma unroll
    for (int o = 32; o > 0; o >>= 1) {
        c0 += __shfl_down(c0, o);
        c1 += __shfl_down(c1, o);
        c2 += __shfl_down(c2, o);
    }
    if (lane == 0) {
        c0 += bs[0]; c1 += bs[1]; c2 += bs[2];
        if (bf) {
            unsigned short* out = (unsigned short*)outv;
            out[(size_t)row * 3 + 0] = f2bf(c0);
            out[(size_t)row * 3 + 1] = f2bf(c1);
            out[(size_t)row * 3 + 2] = f2bf(c2);
        } else {
            float* out = (float*)outv;
            out[(size_t)row * 3 + 0] = c0;
            out[(size_t)row * 3 + 1] = c1;
            out[(size_t)row * 3 + 2] = c2;
        }
    }
}

extern "C" void kernel_launch(void* const* d_in, const int* in_sizes, int n_in,
                              void* d_out, int out_size, void* d_ws, size_t ws_size,
                              hipStream_t stream) {
    const void* x = nullptr; const int* ei = nullptr;
    const void* W1 = nullptr; const void* W5 = nullptr; const void* b5 = nullptr;
    const void* Wmid[3] = {nullptr, nullptr, nullptr};
    const void* bvec[4] = {nullptr, nullptr, nullptr, nullptr};
    int nw = 0, nb = 0;
    for (int i = 0; i < n_in; i++) {
        int s = in_sizes[i];
        if      (s == 50000000) x = d_in[i];
        else if (s == 3200000)  ei = (const int*)d_in[i];
        else if (s == 64000)    W1 = d_in[i];
        else if (s == 16384)  { if (nw < 3) Wmid[nw++] = d_in[i]; }
        else if (s == 384)      W5 = d_in[i];
        else if (s == 128)    { if (nb < 4) bvec[nb++] = d_in[i]; }
        else if (s == 3)        b5 = d_in[i];
    }
    if (!x || !ei || !W1 || !W5 || !b5 || nw < 3 || nb < 4) return;

    char* p = (char*)d_ws;
    auto alloc = [&](size_t bytes) { char* q = p; p += (bytes + 255) & ~(size_t)255; return (void*)q; };
    int*   flags = (int*)alloc(256);
    float* dis   = (float*)alloc((size_t)NNP * 4);
    int*   cnt   = (int*)alloc((size_t)NN * 4);
    int*   off   = (int*)alloc((size_t)(NN + 1) * 4);
    int*   cur   = (int*)alloc((size_t)NN * 4);
    int*   bsum  = (int*)alloc(128 * 4);
    int*   csr   = (int*)alloc((size_t)NE * 4);
    unsigned short* Wt1 = (unsigned short*)alloc((size_t)128 * 512 * 2);
    unsigned short* Wt2 = (unsigned short*)alloc((size_t)128 * 128 * 2);
    unsigned short* Wt3 = (unsigned short*)alloc((size_t)128 * 128 * 2);
    unsigned short* Wt4 = (unsigned short*)alloc((size_t)128 * 128 * 2);
    unsigned short* T   = (unsigned short*)alloc((size_t)NNP * HID * 2);
    unsigned short* H   = (unsigned short*)alloc((size_t)NNP * HID * 2);

    // graph build + weight transposes
    GCNLarge_20761871909627_kernel<<<(NN + 255) / 256, 256, 0, stream>>>(cnt, NN);
    detect_kernel<<<1, 64, 0, stream>>>(ei, (const unsigned int*)x, flags);
    wt_kernel<<<256, 256, 0, stream>>>(W1, flags, Wt1, FIN, 512, 128 * 512);
    wt_kernel<<<64, 256, 0, stream>>>(Wmid[0], flags, Wt2, HID, 128, 128 * 128);
    wt_kernel<<<64, 256, 0, stream>>>(Wmid[1], flags, Wt3, HID, 128, 128 * 128);
    wt_kernel<<<64, 256, 0, stream>>>(Wmid[2], flags, Wt4, HID, 128, 128 * 128);
    count_kernel<<<(NE + 255) / 256, 256, 0, stream>>>(ei, flags, cnt);
    dis_kernel<<<(NNP + 255) / 256, 256, 0, stream>>>(cnt, dis);
    scan1_kernel<<<98, 1024, 0, stream>>>(cnt, off, bsum);
    scan2_kernel<<<1, 64, 0, stream>>>(bsum, 98);
    scan3_kernel<<<98, 1024, 0, stream>>>(off, bsum, cur);
    place_kernel<<<(NE + 255) / 256, 256, 0, stream>>>(ei, flags, cur, csr);

    // layer 1
    gemm1s_kernel<<<NNP / 64, 256, 0, stream>>>(x, Wt1, dis, flags, T);
    aggb_kernel<<<NN / 4, 256, 0, stream>>>(T, off, csr, dis, bvec[0], flags, H, 1, 0);
    // layers 2-4 (T/H ping-pong), 391 blocks x 4 tiles x 64 rows = NNP
    gemmWr_kernel<<<NNP / 256, 256, 0, stream>>>(H, Wt2, dis, T);
    aggb_kernel<<<NN / 4, 256, 0, stream>>>(T, off, csr, dis, bvec[1], flags, H, 1, 0);
    gemmWr_kernel<<<NNP / 256, 256, 0, stream>>>(H, Wt3, dis, T);
    aggb_kernel<<<NN / 4, 256, 0, stream>>>(T, off, csr, dis, bvec[2], flags, H, 1, 0);
    gemmWr_kernel<<<NNP / 256, 256, 0, stream>>>(H, Wt4, dis, T);
    aggb_kernel<<<NN / 4, 256, 0, stream>>>(T, off, csr, dis, bvec[3], flags, H, 1, 0);
    // layer 5: aggregate first (linearity), then small GEMM
    aggb_kernel<<<NN / 4, 256, 0, stream>>>(H, off, csr, dis, nullptr, flags, T, 0, 1);
    gemm5_kernel<<<NN / 4, 256, 0, stream>>>(T, W5, b5, flags, d_out);
}

// Round 6
// 941.885 us; speedup vs baseline: 1.0673x; 1.0538x over previous
//
#include <hip/hip_runtime.h>
#include <hip/hip_bf16.h>

#define NN 100000
#define NNP 100096   // padded rows: multiple of 256
#define NE 1600000
#define FIN 500
#define HID 128

typedef __attribute__((ext_vector_type(8))) short short8;   // 8 bf16 = 4 VGPRs (MFMA A/B frag)
typedef __attribute__((ext_vector_type(4))) float f32x4;    // MFMA C/D frag

__device__ __forceinline__ float bf2f(unsigned short u) {
    return __uint_as_float(((unsigned int)u) << 16);
}
__device__ __forceinline__ unsigned short f2bf(float f) {
    __hip_bfloat16 h = __float2bfloat16(f);
    return *(unsigned short*)&h;
}
__device__ __forceinline__ float lo16(unsigned int v) { return __uint_as_float(v << 16); }
__device__ __forceinline__ float hi16(unsigned int v) { return __uint_as_float(v & 0xffff0000u); }

// direct global->LDS 16B: no result VGPRs, so all staging loads stay in flight.
// LDS dest is wave-uniform base + lane*16 (linear); swizzle lives on the per-lane
// global SOURCE address + matching read-side XOR (both-sides-or-neither, rule 21).
__device__ __forceinline__ void gload_lds16(const void* g, void* l) {
    __builtin_amdgcn_global_load_lds(
        (const __attribute__((address_space(1))) unsigned int*)g,
        (__attribute__((address_space(3))) unsigned int*)l, 16, 0, 0);
}

// ---------- template-named kernel (serves as cnt zeroing) ----------

__global__ __launch_bounds__(256) void GCNLarge_20761871909627_kernel(int* __restrict__ buf, int n) {
    int i = blockIdx.x * 256 + threadIdx.x;
    if (i < n) buf[i] = 0;
}

// ---------- runtime layout detection (wave-parallel) ----------

__global__ void detect_kernel(const int* __restrict__ ei, const unsigned int* __restrict__ xw,
                              int* __restrict__ flags) {
    int lane = threadIdx.x & 63;
    int any = 0;
    for (int k = lane; k < 128; k += 64) any |= ei[2 * k + 1];
    int hits = 0;
    for (int k = lane; k < 256; k += 64) {
        unsigned e = (xw[k] >> 7) & 0xFF;
        hits += (e >= 100 && e <= 140) ? 1 : 0;
    }
#pragma unroll
    for (int o = 32; o > 0; o >>= 1) {
        any |= __shfl_down(any, o);
        hits += __shfl_down(hits, o);
    }
    if (lane == 0) {
        flags[0] = (any == 0) ? 1 : 0;
        flags[1] = (hits >= 128) ? 1 : 0;
    }
}

__device__ __forceinline__ int edge_src(const int* ei, int e, int m) {
    return m ? ei[2 * (size_t)e] : ei[e];
}
__device__ __forceinline__ int edge_dst(const int* ei, int e, int m) {
    return m ? ei[2 * (size_t)NE + 2 * (size_t)e] : ei[(size_t)NE + e];
}

// ---------- degree / CSR build ----------

__global__ __launch_bounds__(256) void count_kernel(const int* __restrict__ ei,
                                                    const int* __restrict__ flags,
                                                    int* __restrict__ cnt) {
    int e = blockIdx.x * 256 + threadIdx.x;
    if (e < NE) {
        int d = edge_dst(ei, e, flags[0]);
        if ((unsigned)d < NN) atomicAdd(&cnt[d], 1);
    }
}

__global__ __launch_bounds__(256) void dis_kernel(const int* __restrict__ cnt,
                                                  float* __restrict__ dis) {
    int i = blockIdx.x * 256 + threadIdx.x;
    if (i < NNP) {
        int c = (i < NN) ? cnt[i] : 0;
        if (c < 0) c = 0;
        dis[i] = rsqrtf((float)(c + 1));
    }
}

__global__ __launch_bounds__(1024) void scan1_kernel(const int* __restrict__ cnt,
                                                     int* __restrict__ off,
                                                     int* __restrict__ bsum) {
    __shared__ int s[1024];
    int i = blockIdx.x * 1024 + threadIdx.x;
    int v = (i < NN) ? cnt[i] : 0;
    s[threadIdx.x] = v;
    __syncthreads();
    for (int d = 1; d < 1024; d <<= 1) {
        int tv = (threadIdx.x >= d) ? s[threadIdx.x - d] : 0;
        __syncthreads();
        s[threadIdx.x] += tv;
        __syncthreads();
    }
    if (i < NN) off[i] = s[threadIdx.x] - v;
    if (threadIdx.x == 1023) bsum[blockIdx.x] = s[1023];
}

__global__ void scan2_kernel(int* __restrict__ bsum, int nb) {
    if (threadIdx.x == 0 && blockIdx.x == 0) {
        int acc = 0;
        for (int b = 0; b < nb; b++) { int v = bsum[b]; bsum[b] = acc; acc += v; }
    }
}

__global__ __launch_bounds__(1024) void scan3_kernel(int* __restrict__ off,
                                                     const int* __restrict__ bsum,
                                                     int* __restrict__ cursor) {
    int i = blockIdx.x * 1024 + threadIdx.x;
    if (i < NN) { int o = off[i] + bsum[blockIdx.x]; off[i] = o; cursor[i] = o; }
    if (i == 0) off[NN] = NE;
}

__global__ __launch_bounds__(256) void place_kernel(const int* __restrict__ ei,
                                                    const int* __restrict__ flags,
                                                    int* __restrict__ cursor,
                                                    int* __restrict__ csr) {
    int e = blockIdx.x * 256 + threadIdx.x;
    if (e < NE) {
        int m = flags[0];
        int s = edge_src(ei, e, m);
        int d = edge_dst(ei, e, m);
        if ((unsigned)s < NN && (unsigned)d < NN) {
            int slot = atomicAdd(&cursor[d], 1);
            if ((unsigned)slot < NE) csr[slot] = s;
        }
    }
}

// ---------- W -> W^T (bf16) in global: Wt[n][k] = W[k][n], zero-padded to Kpad ----------

__global__ __launch_bounds__(256) void wt_kernel(const void* __restrict__ W,
                                                 const int* __restrict__ flags,
                                                 unsigned short* __restrict__ Wt,
                                                 int K, int Kpad, int total) {
    int idx = blockIdx.x * 256 + threadIdx.x;
    if (idx >= total) return;
    int n = idx / Kpad, k = idx - n * Kpad;
    unsigned short v = 0;
    if (k < K) {
        if (flags[1]) v = ((const unsigned short*)W)[(size_t)k * HID + n];
        else          v = f2bf(((const float*)W)[(size_t)k * HID + n]);
    }
    Wt[idx] = v;
}

// ---------- layers 2-4: barrier-free register GEMM ----------

__global__ __launch_bounds__(256) void gemmWr_kernel(const unsigned short* __restrict__ A,
                                                     const unsigned short* __restrict__ Wt,
                                                     const float* __restrict__ dis,
                                                     unsigned short* __restrict__ out) {
    int tid = threadIdx.x;
    int w = tid >> 6, lane = tid & 63;
    int m = lane & 15, quad = lane >> 4;
    int mbase = (w >> 1) * 32, nbase = (w & 1) * 64;
    short8 b[4][4];
#pragma unroll
    for (int nt = 0; nt < 4; nt++)
#pragma unroll
        for (int kq = 0; kq < 4; kq++)
            b[nt][kq] = *(const short8*)(Wt + (size_t)(nbase + nt * 16 + m) * HID + kq * 32 + quad * 8);
    int t0 = blockIdx.x * 4;
    short8 aP[4][2], aQ[4][2];
    auto loadA = [&](int t, short8 a[4][2]) {
        const unsigned short* p0 = A + (size_t)(t * 64 + mbase + m) * HID + quad * 8;
        const unsigned short* p1 = p0 + (size_t)16 * HID;
#pragma unroll
        for (int kq = 0; kq < 4; kq++) {
            a[kq][0] = *(const short8*)(p0 + kq * 32);
            a[kq][1] = *(const short8*)(p1 + kq * 32);
        }
    };
    loadA(t0, aP);
#pragma unroll
    for (int tt = 0; tt < 4; tt++) {
        if (tt < 3) loadA(t0 + tt + 1, (tt & 1) ? aP : aQ);
        short8 (*ac)[2] = (tt & 1) ? aQ : aP;
        f32x4 acc[2][4] = {};
#pragma unroll
        for (int kq = 0; kq < 4; kq++)
#pragma unroll
            for (int nt = 0; nt < 4; nt++) {
                acc[0][nt] = __builtin_amdgcn_mfma_f32_16x16x32_bf16(ac[kq][0], b[nt][kq], acc[0][nt], 0, 0, 0);
                acc[1][nt] = __builtin_amdgcn_mfma_f32_16x16x32_bf16(ac[kq][1], b[nt][kq], acc[1][nt], 0, 0, 0);
            }
        int r0 = (t0 + tt) * 64;
#pragma unroll
        for (int mt = 0; mt < 2; mt++) {
            int rb = r0 + mbase + mt * 16 + quad * 4;
#pragma unroll
            for (int reg = 0; reg < 4; reg++) {
                float d = dis[rb + reg];
#pragma unroll
                for (int nt = 0; nt < 4; nt++)
                    out[(size_t)(rb + reg) * HID + nbase + nt * 16 + m] = f2bf(acc[mt][nt][reg] * d);
            }
        }
    }
}

// ---------- layer 1: x [NN,500] @ Wt1[128][512], global_load_lds staging ----------
// Round-2 post-mortem: 3 structures all ~145us at ~220 cyc per issued VMEM = one
// latency each; reg-staged loads were VGPR-capped to ~4 in flight per wave. Fix:
// global_load_lds (zero result VGPRs) keeps all 16 staging loads/thread in flight.
// LDS dest linear; bank-conflict XOR swizzle applied on the per-lane global source
// chunk index and identically on the frag-read side (involution). fp32->bf16 cvt
// happens at frag read. OOB tail chunks (kc=3, col>=500) clamp source to x[0]:
// finite garbage x B-pad-zero = exact 0.

__global__ __launch_bounds__(256) void gemm1g_kernel(const void* __restrict__ Av,
                                                     const unsigned short* __restrict__ Wt1,
                                                     const float* __restrict__ dis,
                                                     const int* __restrict__ flags,
                                                     unsigned short* __restrict__ out) {
    __shared__ __align__(16) char lds[65536];
    float* AsF         = (float*)lds;                      // fp32 path: A slice [64][128] f32, 32KB
    unsigned short* Bs = (unsigned short*)(lds + 32768);   // B slice [128][128] bf16, 32KB
    unsigned short* As = (unsigned short*)lds;             // bf16 path: A slice [64][128] bf16, 16KB
    int tid = threadIdx.x;
    int bf = flags[1];
    int w = tid >> 6, lane = tid & 63;
    int m = lane & 15, quad = lane >> 4;
    int mbase = (w >> 1) * 32, nbase = (w & 1) * 64;
    int r0 = blockIdx.x * 64;
    f32x4 acc[2][4] = {};
    if (!bf) {
        // ---------------- fp32-x path (bench path) ----------------
#pragma unroll 1
        for (int kc = 0; kc < 4; kc++) {
            // B: 2048 16B slots; slot s=(n,cs) holds global chunk cs^(n&7)
#pragma unroll
            for (int i = 0; i < 8; i++) {
                int base = (i * 4 + w) * 64;
                int s = base + lane;
                int n = s >> 4, cs = s & 15;
                int csrc = cs ^ (n & 7);
                gload_lds16((const char*)Wt1 + (size_t)n * 1024 + kc * 256 + csrc * 16,
                            (char*)Bs + (size_t)base * 16);
            }
            // A: 2048 16B slots (fp32); slot s=(r,cs) holds global chunk cs^(r&7)
#pragma unroll
            for (int i = 0; i < 8; i++) {
                int base = (i * 4 + w) * 64;
                int s = base + lane;
                int r = s >> 5, cs = s & 31;
                int csrc = cs ^ (r & 7);
                int grow = r0 + r; int gr = (grow < NN) ? grow : NN - 1;
                int rb = kc * 512 + csrc * 16;          // byte offset within 2000B row
                size_t gb = (size_t)gr * 2000 + rb;
                if (rb + 16 > 2000) gb = 0;             // clamp OOB tail (x B-pad-zero)
                gload_lds16((const char*)Av + gb, (char*)lds + (size_t)base * 16);
            }
            __syncthreads();   // one vmcnt drain for all 16 loads/thread
#pragma unroll
            for (int kq = 0; kq < 4; kq++) {
                int g = kq * 4 + quad;
                int ra = mbase + m, rb2 = mbase + 16 + m;
                int fa = ra & 7, fb = rb2 & 7;
                float4 x0 = *(const float4*)(AsF + ra  * 128 + (((2 * g)     ^ fa) * 4));
                float4 x1 = *(const float4*)(AsF + ra  * 128 + (((2 * g + 1) ^ fa) * 4));
                float4 y0 = *(const float4*)(AsF + rb2 * 128 + (((2 * g)     ^ fb) * 4));
                float4 y1 = *(const float4*)(AsF + rb2 * 128 + (((2 * g + 1) ^ fb) * 4));
                short8 a0 = short8{(short)f2bf(x0.x), (short)f2bf(x0.y), (short)f2bf(x0.z), (short)f2bf(x0.w),
                                   (short)f2bf(x1.x), (short)f2bf(x1.y), (short)f2bf(x1.z), (short)f2bf(x1.w)};
                short8 a1 = short8{(short)f2bf(y0.x), (short)f2bf(y0.y), (short)f2bf(y0.z), (short)f2bf(y0.w),
                                   (short)f2bf(y1.x), (short)f2bf(y1.y), (short)f2bf(y1.z), (short)f2bf(y1.w)};
#pragma unroll
                for (int nt = 0; nt < 4; nt++) {
                    int n = nbase + nt * 16 + m;
                    short8 b = *(const short8*)(Bs + (size_t)n * 128 + ((g ^ (n & 7)) * 8));
                    acc[0][nt] = __builtin_amdgcn_mfma_f32_16x16x32_bf16(a0, b, acc[0][nt], 0, 0, 0);
                    acc[1][nt] = __builtin_amdgcn_mfma_f32_16x16x32_bf16(a1, b, acc[1][nt], 0, 0, 0);
                }
            }
            __syncthreads();   // protect slices from next kc staging
        }
    } else {
        // ---------------- bf16-x path (round-2 verified reg staging) ----------------
        int srow = tid >> 5;
        int scol = (tid & 31) * 4;
        int schunk = scol >> 3;
        int shalf = (scol >> 2) & 1;
#pragma unroll 1
        for (int kc = 0; kc < 4; kc++) {
#pragma unroll
            for (int it = 0; it < 8; it++) {
                int chunk = it * 256 + tid;
                int n = chunk >> 4, c = chunk & 15;
                int sc = c ^ (n & 15);
                *(short8*)(&Bs[n * 128 + c * 8]) =
                    *(const short8*)(Wt1 + (size_t)n * 512 + kc * 128 + sc * 8);
            }
#pragma unroll
            for (int i = 0; i < 8; i++) {
                int row = i * 8 + srow;
                int grow = r0 + row;
                int gr = (grow < NN) ? grow : NN - 1;
                int gcol = kc * 128 + scol;
                ushort4 pk = make_ushort4(0, 0, 0, 0);
                if (gcol + 4 <= FIN)
                    pk = *(const ushort4*)((const unsigned short*)Av + (size_t)gr * FIN + gcol);
                int pos = schunk ^ (row & 15);
                *(ushort4*)(&As[row * 128 + pos * 8 + shalf * 4]) = pk;
            }
            __syncthreads();
#pragma unroll
            for (int kq = 0; kq < 4; kq++) {
                int g = kq * 4 + quad;
                int ar0 = mbase + m;
                int ar1 = mbase + 16 + m;
                short8 a0 = *(const short8*)(&As[ar0 * 128 + ((g ^ m) * 8)]);
                short8 a1 = *(const short8*)(&As[ar1 * 128 + ((g ^ m) * 8)]);
#pragma unroll
                for (int nt = 0; nt < 4; nt++) {
                    int n = nbase + nt * 16 + m;
                    short8 b = *(const short8*)(&Bs[n * 128 + ((g ^ (n & 15)) * 8)]);
                    acc[0][nt] = __builtin_amdgcn_mfma_f32_16x16x32_bf16(a0, b, acc[0][nt], 0, 0, 0);
                    acc[1][nt] = __builtin_amdgcn_mfma_f32_16x16x32_bf16(a1, b, acc[1][nt], 0, 0, 0);
                }
            }
            __syncthreads();
        }
    }
#pragma unroll
    for (int mt = 0; mt < 2; mt++) {
        int rb = r0 + mbase + mt * 16 + quad * 4;
#pragma unroll
        for (int reg = 0; reg < 4; reg++) {
            int row = rb + reg;
            if (row < NN) {
                float d = dis[row];
#pragma unroll
                for (int nt = 0; nt < 4; nt++)
                    out[(size_t)row * HID + nbase + nt * 16 + m] = f2bf(acc[mt][nt][reg] * d);
            }
        }
    }
}

// ---------- aggregation over bf16 features, f32 accumulate, 8x unrolled ----------

__global__ __launch_bounds__(256) void aggb_kernel(const unsigned short* __restrict__ tin,
                                                   const int* __restrict__ off,
                                                   const int* __restrict__ csr,
                                                   const float* __restrict__ dis,
                                                   const void* __restrict__ bias,
                                                   const int* __restrict__ flags,
                                                   unsigned short* __restrict__ hout,
                                                   int relu, int scale_src) {
    int node = blockIdx.x * 4 + (threadIdx.x >> 6);   // one wave per node
    int lane = threadIdx.x & 63;                      // 2 features per lane (1 dword)
    float di = dis[node];
    unsigned int sv = *(const unsigned int*)(tin + (size_t)node * HID + lane * 2);
    float acc0 = scale_src ? di * lo16(sv) : lo16(sv);
    float acc1 = scale_src ? di * hi16(sv) : hi16(sv);
    int e0 = off[node], e1 = off[node + 1];
    if (e0 < 0) e0 = 0;
    if (e1 > NE) e1 = NE;
    int e = e0;
    if (!scale_src) {
        for (; e + 8 <= e1; e += 8) {
            int i0 = csr[e],     i1 = csr[e + 1], i2 = csr[e + 2], i3 = csr[e + 3];
            int i4 = csr[e + 4], i5 = csr[e + 5], i6 = csr[e + 6], i7 = csr[e + 7];
            unsigned int v0 = *(const unsigned int*)(tin + (size_t)i0 * HID + lane * 2);
            unsigned int v1 = *(const unsigned int*)(tin + (size_t)i1 * HID + lane * 2);
            unsigned int v2 = *(const unsigned int*)(tin + (size_t)i2 * HID + lane * 2);
            unsigned int v3 = *(const unsigned int*)(tin + (size_t)i3 * HID + lane * 2);
            unsigned int v4 = *(const unsigned int*)(tin + (size_t)i4 * HID + lane * 2);
            unsigned int v5 = *(const unsigned int*)(tin + (size_t)i5 * HID + lane * 2);
            unsigned int v6 = *(const unsigned int*)(tin + (size_t)i6 * HID + lane * 2);
            unsigned int v7 = *(const unsigned int*)(tin + (size_t)i7 * HID + lane * 2);
            acc0 += lo16(v0); acc1 += hi16(v0); acc0 += lo16(v1); acc1 += hi16(v1);
            acc0 += lo16(v2); acc1 += hi16(v2); acc0 += lo16(v3); acc1 += hi16(v3);
            acc0 += lo16(v4); acc1 += hi16(v4); acc0 += lo16(v5); acc1 += hi16(v5);
            acc0 += lo16(v6); acc1 += hi16(v6); acc0 += lo16(v7); acc1 += hi16(v7);
        }
        for (; e + 4 <= e1; e += 4) {
            int i0 = csr[e], i1 = csr[e + 1], i2 = csr[e + 2], i3 = csr[e + 3];
            unsigned int v0 = *(const unsigned int*)(tin + (size_t)i0 * HID + lane * 2);
            unsigned int v1 = *(const unsigned int*)(tin + (size_t)i1 * HID + lane * 2);
            unsigned int v2 = *(const unsigned int*)(tin + (size_t)i2 * HID + lane * 2);
            unsigned int v3 = *(const unsigned int*)(tin + (size_t)i3 * HID + lane * 2);
            acc0 += lo16(v0); acc1 += hi16(v0); acc0 += lo16(v1); acc1 += hi16(v1);
            acc0 += lo16(v2); acc1 += hi16(v2); acc0 += lo16(v3); acc1 += hi16(v3);
        }
        for (; e < e1; e++) {
            int s = csr[e];
            unsigned int v = *(const unsigned int*)(tin + (size_t)s * HID + lane * 2);
            acc0 += lo16(v); acc1 += hi16(v);
        }
    } else {
        for (; e + 8 <= e1; e += 8) {
            int i0 = csr[e],     i1 = csr[e + 1], i2 = csr[e + 2], i3 = csr[e + 3];
            int i4 = csr[e + 4], i5 = csr[e + 5], i6 = csr[e + 6], i7 = csr[e + 7];
            unsigned int v0 = *(const unsigned int*)(tin + (size_t)i0 * HID + lane * 2);
            unsigned int v1 = *(const unsigned int*)(tin + (size_t)i1 * HID + lane * 2);
            unsigned int v2 = *(const unsigned int*)(tin + (size_t)i2 * HID + lane * 2);
            unsigned int v3 = *(const unsigned int*)(tin + (size_t)i3 * HID + lane * 2);
            unsigned int v4 = *(const unsigned int*)(tin + (size_t)i4 * HID + lane * 2);
            unsigned int v5 = *(const unsigned int*)(tin + (size_t)i5 * HID + lane * 2);
            unsigned int v6 = *(const unsigned int*)(tin + (size_t)i6 * HID + lane * 2);
            unsigned int v7 = *(const unsigned int*)(tin + (size_t)i7 * HID + lane * 2);
            float m0 = dis[i0], m1 = dis[i1], m2 = dis[i2], m3 = dis[i3];
            float m4 = dis[i4], m5 = dis[i5], m6 = dis[i6], m7 = dis[i7];
            acc0 += m0 * lo16(v0); acc1 += m0 * hi16(v0);
            acc0 += m1 * lo16(v1); acc1 += m1 * hi16(v1);
            acc0 += m2 * lo16(v2); acc1 += m2 * hi16(v2);
            acc0 += m3 * lo16(v3); acc1 += m3 * hi16(v3);
            acc0 += m4 * lo16(v4); acc1 += m4 * hi16(v4);
            acc0 += m5 * lo16(v5); acc1 += m5 * hi16(v5);
            acc0 += m6 * lo16(v6); acc1 += m6 * hi16(v6);
            acc0 += m7 * lo16(v7); acc1 += m7 * hi16(v7);
        }
        for (; e < e1; e++) {
            int s = csr[e];
            unsigned int v = *(const unsigned int*)(tin + (size_t)s * HID + lane * 2);
            float mm = dis[s];
            acc0 += mm * lo16(v); acc1 += mm * hi16(v);
        }
    }
    float o0 = di * acc0, o1 = di * acc1;
    if (bias) {
        if (flags[1]) { o0 += bf2f(((const unsigned short*)bias)[lane * 2]);
                        o1 += bf2f(((const unsigned short*)bias)[lane * 2 + 1]); }
        else          { o0 += ((const float*)bias)[lane * 2];
                        o1 += ((const float*)bias)[lane * 2 + 1]; }
    }
    if (relu) { o0 = fmaxf(o0, 0.f); o1 = fmaxf(o1, 0.f); }
    unsigned int pk = ((unsigned int)f2bf(o1) << 16) | (unsigned int)f2bf(o0);
    *(unsigned int*)(hout + (size_t)node * HID + lane * 2) = pk;
}

// ---------- layer 5: bf16 [NN,128] @ W5 [128,3] + b5 -> out (dtype per flags[1]) ----------

__global__ __launch_bounds__(256) void gemm5_kernel(const unsigned short* __restrict__ A,
                                                    const void* __restrict__ W5v,
                                                    const void* __restrict__ b5v,
                                                    const int* __restrict__ flags,
                                                    void* __restrict__ outv) {
    __shared__ float Ws[384];
    __shared__ float bs[3];
    int tid = threadIdx.x;
    int bf = flags[1];
    for (int idx = tid; idx < 384; idx += 256)
        Ws[idx] = bf ? bf2f(((const unsigned short*)W5v)[idx]) : ((const float*)W5v)[idx];
    if (tid < 3)
        bs[tid] = bf ? bf2f(((const unsigned short*)b5v)[tid]) : ((const float*)b5v)[tid];
    __syncthreads();
    int lane = tid & 63;
    int row = blockIdx.x * 4 + (tid >> 6);
    float a0 = bf2f(A[(size_t)row * HID + lane]);
    float a1 = bf2f(A[(size_t)row * HID + 64 + lane]);
    float c0 = a0 * Ws[lane * 3 + 0] + a1 * Ws[(lane + 64) * 3 + 0];
    float c1 = a0 * Ws[lane * 3 + 1] + a1 * Ws[(lane + 64) * 3 + 1];
    float c2 = a0 * Ws[lane * 3 + 2] + a1 * Ws[(lane + 64) * 3 + 2];
#pragma unroll
    for (int o = 32; o > 0; o >>= 1) {
        c0 += __shfl_down(c0, o);
        c1 += __shfl_down(c1, o);
        c2 += __shfl_down(c2, o);
    }
    if (lane == 0) {
        c0 += bs[0]; c1 += bs[1]; c2 += bs[2];
        if (bf) {
            unsigned short* out = (unsigned short*)outv;
            out[(size_t)row * 3 + 0] = f2bf(c0);
            out[(size_t)row * 3 + 1] = f2bf(c1);
            out[(size_t)row * 3 + 2] = f2bf(c2);
        } else {
            float* out = (float*)outv;
            out[(size_t)row * 3 + 0] = c0;
            out[(size_t)row * 3 + 1] = c1;
            out[(size_t)row * 3 + 2] = c2;
        }
    }
}

extern "C" void kernel_launch(void* const* d_in, const int* in_sizes, int n_in,
                              void* d_out, int out_size, void* d_ws, size_t ws_size,
                              hipStream_t stream) {
    const void* x = nullptr; const int* ei = nullptr;
    const void* W1 = nullptr; const void* W5 = nullptr; const void* b5 = nullptr;
    const void* Wmid[3] = {nullptr, nullptr, nullptr};
    const void* bvec[4] = {nullptr, nullptr, nullptr, nullptr};
    int nw = 0, nb = 0;
    for (int i = 0; i < n_in; i++) {
        int s = in_sizes[i];
        if      (s == 50000000) x = d_in[i];
        else if (s == 3200000)  ei = (const int*)d_in[i];
        else if (s == 64000)    W1 = d_in[i];
        else if (s == 16384)  { if (nw < 3) Wmid[nw++] = d_in[i]; }
        else if (s == 384)      W5 = d_in[i];
        else if (s == 128)    { if (nb < 4) bvec[nb++] = d_in[i]; }
        else if (s == 3)        b5 = d_in[i];
    }
    if (!x || !ei || !W1 || !W5 || !b5 || nw < 3 || nb < 4) return;

    char* p = (char*)d_ws;
    auto alloc = [&](size_t bytes) { char* q = p; p += (bytes + 255) & ~(size_t)255; return (void*)q; };
    int*   flags = (int*)alloc(256);
    float* dis   = (float*)alloc((size_t)NNP * 4);
    int*   cnt   = (int*)alloc((size_t)NN * 4);
    int*   off   = (int*)alloc((size_t)(NN + 1) * 4);
    int*   cur   = (int*)alloc((size_t)NN * 4);
    int*   bsum  = (int*)alloc(128 * 4);
    int*   csr   = (int*)alloc((size_t)NE * 4);
    unsigned short* Wt1 = (unsigned short*)alloc((size_t)128 * 512 * 2);
    unsigned short* Wt2 = (unsigned short*)alloc((size_t)128 * 128 * 2);
    unsigned short* Wt3 = (unsigned short*)alloc((size_t)128 * 128 * 2);
    unsigned short* Wt4 = (unsigned short*)alloc((size_t)128 * 128 * 2);
    unsigned short* T   = (unsigned short*)alloc((size_t)NNP * HID * 2);
    unsigned short* H   = (unsigned short*)alloc((size_t)NNP * HID * 2);

    // graph build + weight transposes
    GCNLarge_20761871909627_kernel<<<(NN + 255) / 256, 256, 0, stream>>>(cnt, NN);
    detect_kernel<<<1, 64, 0, stream>>>(ei, (const unsigned int*)x, flags);
    wt_kernel<<<256, 256, 0, stream>>>(W1, flags, Wt1, FIN, 512, 128 * 512);
    wt_kernel<<<64, 256, 0, stream>>>(Wmid[0], flags, Wt2, HID, 128, 128 * 128);
    wt_kernel<<<64, 256, 0, stream>>>(Wmid[1], flags, Wt3, HID, 128, 128 * 128);
    wt_kernel<<<64, 256, 0, stream>>>(Wmid[2], flags, Wt4, HID, 128, 128 * 128);
    count_kernel<<<(NE + 255) / 256, 256, 0, stream>>>(ei, flags, cnt);
    dis_kernel<<<(NNP + 255) / 256, 256, 0, stream>>>(cnt, dis);
    scan1_kernel<<<98, 1024, 0, stream>>>(cnt, off, bsum);
    scan2_kernel<<<1, 64, 0, stream>>>(bsum, 98);
    scan3_kernel<<<98, 1024, 0, stream>>>(off, bsum, cur);
    place_kernel<<<(NE + 255) / 256, 256, 0, stream>>>(ei, flags, cur, csr);

    // layer 1
    gemm1g_kernel<<<NNP / 64, 256, 0, stream>>>(x, Wt1, dis, flags, T);
    aggb_kernel<<<NN / 4, 256, 0, stream>>>(T, off, csr, dis, bvec[0], flags, H, 1, 0);
    // layers 2-4 (T/H ping-pong), 391 blocks x 4 tiles x 64 rows = NNP
    gemmWr_kernel<<<NNP / 256, 256, 0, stream>>>(H, Wt2, dis, T);
    aggb_kernel<<<NN / 4, 256, 0, stream>>>(T, off, csr, dis, bvec[1], flags, H, 1, 0);
    gemmWr_kernel<<<NNP / 256, 256, 0, stream>>>(H, Wt3, dis, T);
    aggb_kernel<<<NN / 4, 256, 0, stream>>>(T, off, csr, dis, bvec[2], flags, H, 1, 0);
    gemmWr_kernel<<<NNP / 256, 256, 0, stream>>>(H, Wt4, dis, T);
    aggb_kernel<<<NN / 4, 256, 0, stream>>>(T, off, csr, dis, bvec[3], flags, H, 1, 0);
    // layer 5: aggregate first (linearity), then small GEMM
    aggb_kernel<<<NN / 4, 256, 0, stream>>>(H, off, csr, dis, nullptr, flags, T, 0, 1);
    gemm5_kernel<<<NN / 4, 256, 0, stream>>>(T, W5, b5, flags, d_out);
}

// Round 8
// 868.758 us; speedup vs baseline: 1.1571x; 1.0842x over previous
//
#include <hip/hip_runtime.h>
#include <hip/hip_bf16.h>

#define NN 100000
#define NNP 100096   // padded rows: multiple of 256
#define NE 1600000
#define FIN 500
#define HID 128

typedef __attribute__((ext_vector_type(8))) short short8;   // 8 bf16 = 4 VGPRs (MFMA A/B frag)
typedef __attribute__((ext_vector_type(4))) float f32x4;    // MFMA C/D frag

__device__ __forceinline__ float bf2f(unsigned short u) {
    return __uint_as_float(((unsigned int)u) << 16);
}
__device__ __forceinline__ unsigned short f2bf(float f) {
    __hip_bfloat16 h = __float2bfloat16(f);
    return *(unsigned short*)&h;
}
__device__ __forceinline__ float lo16(unsigned int v) { return __uint_as_float(v << 16); }
__device__ __forceinline__ float hi16(unsigned int v) { return __uint_as_float(v & 0xffff0000u); }

// direct global->LDS 16B: no result VGPRs, so all staging loads stay in flight.
__device__ __forceinline__ void gload_lds16(const void* g, void* l) {
    __builtin_amdgcn_global_load_lds(
        (const __attribute__((address_space(1))) unsigned int*)g,
        (__attribute__((address_space(3))) unsigned int*)l, 16, 0, 0);
}

// ---------- template-named kernel (serves as cnt zeroing) ----------

__global__ __launch_bounds__(256) void GCNLarge_20761871909627_kernel(int* __restrict__ buf, int n) {
    int i = blockIdx.x * 256 + threadIdx.x;
    if (i < n) buf[i] = 0;
}

// ---------- runtime layout detection (wave-parallel) ----------

__global__ void detect_kernel(const int* __restrict__ ei, const unsigned int* __restrict__ xw,
                              int* __restrict__ flags) {
    int lane = threadIdx.x & 63;
    int any = 0;
    for (int k = lane; k < 128; k += 64) any |= ei[2 * k + 1];
    int hits = 0;
    for (int k = lane; k < 256; k += 64) {
        unsigned e = (xw[k] >> 7) & 0xFF;
        hits += (e >= 100 && e <= 140) ? 1 : 0;
    }
#pragma unroll
    for (int o = 32; o > 0; o >>= 1) {
        any |= __shfl_down(any, o);
        hits += __shfl_down(hits, o);
    }
    if (lane == 0) {
        flags[0] = (any == 0) ? 1 : 0;
        flags[1] = (hits >= 128) ? 1 : 0;
    }
}

__device__ __forceinline__ int edge_src(const int* ei, int e, int m) {
    return m ? ei[2 * (size_t)e] : ei[e];
}
__device__ __forceinline__ int edge_dst(const int* ei, int e, int m) {
    return m ? ei[2 * (size_t)NE + 2 * (size_t)e] : ei[(size_t)NE + e];
}

// ---------- degree / CSR build ----------
// Round-6 post-mortem: place_kernel was the #1 dispatch (140us): every edge paid a
// device-scope atomic-with-return (cursor) PLUS count's fire-and-forget atomic = 2
// random atomics per edge, plus the scattered csr store (WRITE_SIZE 105MB for a 6.4MB
// array = ~16 writebacks/line from cross-XCD dirtying). Fix: count's atomic return IS
// the edge's rank within its dst -> store rank[e], and place becomes atomic-free:
// csr[off[d]+rank[e]] = s. Atomics halve (3.2M -> 1.6M). 4-edge unroll for MLP.

__global__ __launch_bounds__(256) void count_kernel(const int* __restrict__ ei,
                                                    const int* __restrict__ flags,
                                                    int* __restrict__ cnt,
                                                    int* __restrict__ rank) {
    int m = flags[0];
    int base = blockIdx.x * 1024 + threadIdx.x;
#pragma unroll
    for (int i = 0; i < 4; i++) {
        int e = base + i * 256;
        if (e < NE) {
            int d = edge_dst(ei, e, m);
            if ((unsigned)d < NN) rank[e] = atomicAdd(&cnt[d], 1);
        }
    }
}

__global__ __launch_bounds__(256) void dis_kernel(const int* __restrict__ cnt,
                                                  float* __restrict__ dis) {
    int i = blockIdx.x * 256 + threadIdx.x;
    if (i < NNP) {
        int c = (i < NN) ? cnt[i] : 0;
        if (c < 0) c = 0;
        dis[i] = rsqrtf((float)(c + 1));
    }
}

__global__ __launch_bounds__(1024) void scan1_kernel(const int* __restrict__ cnt,
                                                     int* __restrict__ off,
                                                     int* __restrict__ bsum) {
    __shared__ int s[1024];
    int i = blockIdx.x * 1024 + threadIdx.x;
    int v = (i < NN) ? cnt[i] : 0;
    s[threadIdx.x] = v;
    __syncthreads();
    for (int d = 1; d < 1024; d <<= 1) {
        int tv = (threadIdx.x >= d) ? s[threadIdx.x - d] : 0;
        __syncthreads();
        s[threadIdx.x] += tv;
        __syncthreads();
    }
    if (i < NN) off[i] = s[threadIdx.x] - v;
    if (threadIdx.x == 1023) bsum[blockIdx.x] = s[1023];
}

__global__ void scan2_kernel(int* __restrict__ bsum, int nb) {
    if (threadIdx.x == 0 && blockIdx.x == 0) {
        int acc = 0;
        for (int b = 0; b < nb; b++) { int v = bsum[b]; bsum[b] = acc; acc += v; }
    }
}

__global__ __launch_bounds__(1024) void scan3_kernel(int* __restrict__ off,
                                                     const int* __restrict__ bsum) {
    int i = blockIdx.x * 1024 + threadIdx.x;
    if (i < NN) off[i] = off[i] + bsum[blockIdx.x];
    if (i == 0) off[NN] = NE;
}

// atomic-free placement: slot = off[d] + rank[e] (unique by construction)
__global__ __launch_bounds__(256) void place_kernel(const int* __restrict__ ei,
                                                    const int* __restrict__ flags,
                                                    const int* __restrict__ off,
                                                    const int* __restrict__ rank,
                                                    int* __restrict__ csr) {
    int m = flags[0];
    int base = blockIdx.x * 1024 + threadIdx.x;
#pragma unroll
    for (int i = 0; i < 4; i++) {
        int e = base + i * 256;
        if (e < NE) {
            int s = edge_src(ei, e, m);
            int d = edge_dst(ei, e, m);
            if ((unsigned)s < NN && (unsigned)d < NN) {
                int slot = off[d] + rank[e];
                if ((unsigned)slot < NE) csr[slot] = s;
            }
        }
    }
}

// ---------- W -> W^T (bf16) in global: Wt[n][k] = W[k][n], zero-padded to Kpad ----------

__global__ __launch_bounds__(256) void wt_kernel(const void* __restrict__ W,
                                                 const int* __restrict__ flags,
                                                 unsigned short* __restrict__ Wt,
                                                 int K, int Kpad, int total) {
    int idx = blockIdx.x * 256 + threadIdx.x;
    if (idx >= total) return;
    int n = idx / Kpad, k = idx - n * Kpad;
    unsigned short v = 0;
    if (k < K) {
        if (flags[1]) v = ((const unsigned short*)W)[(size_t)k * HID + n];
        else          v = f2bf(((const float*)W)[(size_t)k * HID + n]);
    }
    Wt[idx] = v;
}

// ---------- layers 2-4: barrier-free register GEMM ----------

__global__ __launch_bounds__(256) void gemmWr_kernel(const unsigned short* __restrict__ A,
                                                     const unsigned short* __restrict__ Wt,
                                                     const float* __restrict__ dis,
                                                     unsigned short* __restrict__ out) {
    int tid = threadIdx.x;
    int w = tid >> 6, lane = tid & 63;
    int m = lane & 15, quad = lane >> 4;
    int mbase = (w >> 1) * 32, nbase = (w & 1) * 64;
    short8 b[4][4];
#pragma unroll
    for (int nt = 0; nt < 4; nt++)
#pragma unroll
        for (int kq = 0; kq < 4; kq++)
            b[nt][kq] = *(const short8*)(Wt + (size_t)(nbase + nt * 16 + m) * HID + kq * 32 + quad * 8);
    int t0 = blockIdx.x * 4;
    short8 aP[4][2], aQ[4][2];
    auto loadA = [&](int t, short8 a[4][2]) {
        const unsigned short* p0 = A + (size_t)(t * 64 + mbase + m) * HID + quad * 8;
        const unsigned short* p1 = p0 + (size_t)16 * HID;
#pragma unroll
        for (int kq = 0; kq < 4; kq++) {
            a[kq][0] = *(const short8*)(p0 + kq * 32);
            a[kq][1] = *(const short8*)(p1 + kq * 32);
        }
    };
    loadA(t0, aP);
#pragma unroll
    for (int tt = 0; tt < 4; tt++) {
        if (tt < 3) loadA(t0 + tt + 1, (tt & 1) ? aP : aQ);
        short8 (*ac)[2] = (tt & 1) ? aQ : aP;
        f32x4 acc[2][4] = {};
#pragma unroll
        for (int kq = 0; kq < 4; kq++)
#pragma unroll
            for (int nt = 0; nt < 4; nt++) {
                acc[0][nt] = __builtin_amdgcn_mfma_f32_16x16x32_bf16(ac[kq][0], b[nt][kq], acc[0][nt], 0, 0, 0);
                acc[1][nt] = __builtin_amdgcn_mfma_f32_16x16x32_bf16(ac[kq][1], b[nt][kq], acc[1][nt], 0, 0, 0);
            }
        int r0 = (t0 + tt) * 64;
#pragma unroll
        for (int mt = 0; mt < 2; mt++) {
            int rb = r0 + mbase + mt * 16 + quad * 4;
#pragma unroll
            for (int reg = 0; reg < 4; reg++) {
                float d = dis[rb + reg];
#pragma unroll
                for (int nt = 0; nt < 4; nt++)
                    out[(size_t)(rb + reg) * HID + nbase + nt * 16 + m] = f2bf(acc[mt][nt][reg] * d);
            }
        }
    }
}

// ---------- layer 1: x [NN,500] @ Wt1[128][512], global_load_lds staging ----------

__global__ __launch_bounds__(256) void gemm1g_kernel(const void* __restrict__ Av,
                                                     const unsigned short* __restrict__ Wt1,
                                                     const float* __restrict__ dis,
                                                     const int* __restrict__ flags,
                                                     unsigned short* __restrict__ out) {
    __shared__ __align__(16) char lds[65536];
    float* AsF         = (float*)lds;                      // fp32 path: A slice [64][128] f32, 32KB
    unsigned short* Bs = (unsigned short*)(lds + 32768);   // B slice [128][128] bf16, 32KB
    unsigned short* As = (unsigned short*)lds;             // bf16 path: A slice [64][128] bf16, 16KB
    int tid = threadIdx.x;
    int bf = flags[1];
    int w = tid >> 6, lane = tid & 63;
    int m = lane & 15, quad = lane >> 4;
    int mbase = (w >> 1) * 32, nbase = (w & 1) * 64;
    int r0 = blockIdx.x * 64;
    f32x4 acc[2][4] = {};
    if (!bf) {
        // ---------------- fp32-x path (bench path) ----------------
#pragma unroll 1
        for (int kc = 0; kc < 4; kc++) {
            // B: 2048 16B slots; slot s=(n,cs) holds global chunk cs^(n&7)
#pragma unroll
            for (int i = 0; i < 8; i++) {
                int base = (i * 4 + w) * 64;
                int s = base + lane;
                int n = s >> 4, cs = s & 15;
                int csrc = cs ^ (n & 7);
                gload_lds16((const char*)Wt1 + (size_t)n * 1024 + kc * 256 + csrc * 16,
                            (char*)Bs + (size_t)base * 16);
            }
            // A: 2048 16B slots (fp32); slot s=(r,cs) holds global chunk cs^(r&7)
#pragma unroll
            for (int i = 0; i < 8; i++) {
                int base = (i * 4 + w) * 64;
                int s = base + lane;
                int r = s >> 5, cs = s & 31;
                int csrc = cs ^ (r & 7);
                int grow = r0 + r; int gr = (grow < NN) ? grow : NN - 1;
                int rb = kc * 512 + csrc * 16;          // byte offset within 2000B row
                size_t gb = (size_t)gr * 2000 + rb;
                if (rb + 16 > 2000) gb = 0;             // clamp OOB tail (x B-pad-zero)
                gload_lds16((const char*)Av + gb, (char*)lds + (size_t)base * 16);
            }
            __syncthreads();   // one vmcnt drain for all 16 loads/thread
#pragma unroll
            for (int kq = 0; kq < 4; kq++) {
                int g = kq * 4 + quad;
                int ra = mbase + m, rb2 = mbase + 16 + m;
                int fa = ra & 7, fb = rb2 & 7;
                float4 x0 = *(const float4*)(AsF + ra  * 128 + (((2 * g)     ^ fa) * 4));
                float4 x1 = *(const float4*)(AsF + ra  * 128 + (((2 * g + 1) ^ fa) * 4));
                float4 y0 = *(const float4*)(AsF + rb2 * 128 + (((2 * g)     ^ fb) * 4));
                float4 y1 = *(const float4*)(AsF + rb2 * 128 + (((2 * g + 1) ^ fb) * 4));
                short8 a0 = short8{(short)f2bf(x0.x), (short)f2bf(x0.y), (short)f2bf(x0.z), (short)f2bf(x0.w),
                                   (short)f2bf(x1.x), (short)f2bf(x1.y), (short)f2bf(x1.z), (short)f2bf(x1.w)};
                short8 a1 = short8{(short)f2bf(y0.x), (short)f2bf(y0.y), (short)f2bf(y0.z), (short)f2bf(y0.w),
                                   (short)f2bf(y1.x), (short)f2bf(y1.y), (short)f2bf(y1.z), (short)f2bf(y1.w)};
#pragma unroll
                for (int nt = 0; nt < 4; nt++) {
                    int n = nbase + nt * 16 + m;
                    short8 b = *(const short8*)(Bs + (size_t)n * 128 + ((g ^ (n & 7)) * 8));
                    acc[0][nt] = __builtin_amdgcn_mfma_f32_16x16x32_bf16(a0, b, acc[0][nt], 0, 0, 0);
                    acc[1][nt] = __builtin_amdgcn_mfma_f32_16x16x32_bf16(a1, b, acc[1][nt], 0, 0, 0);
                }
            }
            __syncthreads();   // protect slices from next kc staging
        }
    } else {
        // ---------------- bf16-x path (round-2 verified reg staging) ----------------
        int srow = tid >> 5;
        int scol = (tid & 31) * 4;
        int schunk = scol >> 3;
        int shalf = (scol >> 2) & 1;
#pragma unroll 1
        for (int kc = 0; kc < 4; kc++) {
#pragma unroll
            for (int it = 0; it < 8; it++) {
                int chunk = it * 256 + tid;
                int n = chunk >> 4, c = chunk & 15;
                int sc = c ^ (n & 15);
                *(short8*)(&Bs[n * 128 + c * 8]) =
                    *(const short8*)(Wt1 + (size_t)n * 512 + kc * 128 + sc * 8);
            }
#pragma unroll
            for (int i = 0; i < 8; i++) {
                int row = i * 8 + srow;
                int grow = r0 + row;
                int gr = (grow < NN) ? grow : NN - 1;
                int gcol = kc * 128 + scol;
                ushort4 pk = make_ushort4(0, 0, 0, 0);
                if (gcol + 4 <= FIN)
                    pk = *(const ushort4*)((const unsigned short*)Av + (size_t)gr * FIN + gcol);
                int pos = schunk ^ (row & 15);
                *(ushort4*)(&As[row * 128 + pos * 8 + shalf * 4]) = pk;
            }
            __syncthreads();
#pragma unroll
            for (int kq = 0; kq < 4; kq++) {
                int g = kq * 4 + quad;
                int ar0 = mbase + m;
                int ar1 = mbase + 16 + m;
                short8 a0 = *(const short8*)(&As[ar0 * 128 + ((g ^ m) * 8)]);
                short8 a1 = *(const short8*)(&As[ar1 * 128 + ((g ^ m) * 8)]);
#pragma unroll
                for (int nt = 0; nt < 4; nt++) {
                    int n = nbase + nt * 16 + m;
                    short8 b = *(const short8*)(&Bs[n * 128 + ((g ^ (n & 15)) * 8)]);
                    acc[0][nt] = __builtin_amdgcn_mfma_f32_16x16x32_bf16(a0, b, acc[0][nt], 0, 0, 0);
                    acc[1][nt] = __builtin_amdgcn_mfma_f32_16x16x32_bf16(a1, b, acc[1][nt], 0, 0, 0);
                }
            }
            __syncthreads();
        }
    }
#pragma unroll
    for (int mt = 0; mt < 2; mt++) {
        int rb = r0 + mbase + mt * 16 + quad * 4;
#pragma unroll
        for (int reg = 0; reg < 4; reg++) {
            int row = rb + reg;
            if (row < NN) {
                float d = dis[row];
#pragma unroll
                for (int nt = 0; nt < 4; nt++)
                    out[(size_t)row * HID + nbase + nt * 16 + m] = f2bf(acc[mt][nt][reg] * d);
            }
        }
    }
}

// ---------- aggregation over bf16 features, f32 accumulate, 8x unrolled ----------

__global__ __launch_bounds__(256) void aggb_kernel(const unsigned short* __restrict__ tin,
                                                   const int* __restrict__ off,
                                                   const int* __restrict__ csr,
                                                   const float* __restrict__ dis,
                                                   const void* __restrict__ bias,
                                                   const int* __restrict__ flags,
                                                   unsigned short* __restrict__ hout,
                                                   int relu, int scale_src) {
    int node = blockIdx.x * 4 + (threadIdx.x >> 6);   // one wave per node
    int lane = threadIdx.x & 63;                      // 2 features per lane (1 dword)
    float di = dis[node];
    unsigned int sv = *(const unsigned int*)(tin + (size_t)node * HID + lane * 2);
    float acc0 = scale_src ? di * lo16(sv) : lo16(sv);
    float acc1 = scale_src ? di * hi16(sv) : hi16(sv);
    int e0 = off[node], e1 = off[node + 1];
    if (e0 < 0) e0 = 0;
    if (e1 > NE) e1 = NE;
    int e = e0;
    if (!scale_src) {
        for (; e + 8 <= e1; e += 8) {
            int i0 = csr[e],     i1 = csr[e + 1], i2 = csr[e + 2], i3 = csr[e + 3];
            int i4 = csr[e + 4], i5 = csr[e + 5], i6 = csr[e + 6], i7 = csr[e + 7];
            unsigned int v0 = *(const unsigned int*)(tin + (size_t)i0 * HID + lane * 2);
            unsigned int v1 = *(const unsigned int*)(tin + (size_t)i1 * HID + lane * 2);
            unsigned int v2 = *(const unsigned int*)(tin + (size_t)i2 * HID + lane * 2);
            unsigned int v3 = *(const unsigned int*)(tin + (size_t)i3 * HID + lane * 2);
            unsigned int v4 = *(const unsigned int*)(tin + (size_t)i4 * HID + lane * 2);
            unsigned int v5 = *(const unsigned int*)(tin + (size_t)i5 * HID + lane * 2);
            unsigned int v6 = *(const unsigned int*)(tin + (size_t)i6 * HID + lane * 2);
            unsigned int v7 = *(const unsigned int*)(tin + (size_t)i7 * HID + lane * 2);
            acc0 += lo16(v0); acc1 += hi16(v0); acc0 += lo16(v1); acc1 += hi16(v1);
            acc0 += lo16(v2); acc1 += hi16(v2); acc0 += lo16(v3); acc1 += hi16(v3);
            acc0 += lo16(v4); acc1 += hi16(v4); acc0 += lo16(v5); acc1 += hi16(v5);
            acc0 += lo16(v6); acc1 += hi16(v6); acc0 += lo16(v7); acc1 += hi16(v7);
        }
        for (; e + 4 <= e1; e += 4) {
            int i0 = csr[e], i1 = csr[e + 1], i2 = csr[e + 2], i3 = csr[e + 3];
            unsigned int v0 = *(const unsigned int*)(tin + (size_t)i0 * HID + lane * 2);
            unsigned int v1 = *(const unsigned int*)(tin + (size_t)i1 * HID + lane * 2);
            unsigned int v2 = *(const unsigned int*)(tin + (size_t)i2 * HID + lane * 2);
            unsigned int v3 = *(const unsigned int*)(tin + (size_t)i3 * HID + lane * 2);
            acc0 += lo16(v0); acc1 += hi16(v0); acc0 += lo16(v1); acc1 += hi16(v1);
            acc0 += lo16(v2); acc1 += hi16(v2); acc0 += lo16(v3); acc1 += hi16(v3);
        }
        for (; e < e1; e++) {
            int s = csr[e];
            unsigned int v = *(const unsigned int*)(tin + (size_t)s * HID + lane * 2);
            acc0 += lo16(v); acc1 += hi16(v);
        }
    } else {
        for (; e + 8 <= e1; e += 8) {
            int i0 = csr[e],     i1 = csr[e + 1], i2 = csr[e + 2], i3 = csr[e + 3];
            int i4 = csr[e + 4], i5 = csr[e + 5], i6 = csr[e + 6], i7 = csr[e + 7];
            unsigned int v0 = *(const unsigned int*)(tin + (size_t)i0 * HID + lane * 2);
            unsigned int v1 = *(const unsigned int*)(tin + (size_t)i1 * HID + lane * 2);
            unsigned int v2 = *(const unsigned int*)(tin + (size_t)i2 * HID + lane * 2);
            unsigned int v3 = *(const unsigned int*)(tin + (size_t)i3 * HID + lane * 2);
            unsigned int v4 = *(const unsigned int*)(tin + (size_t)i4 * HID + lane * 2);
            unsigned int v5 = *(const unsigned int*)(tin + (size_t)i5 * HID + lane * 2);
            unsigned int v6 = *(const unsigned int*)(tin + (size_t)i6 * HID + lane * 2);
            unsigned int v7 = *(const unsigned int*)(tin + (size_t)i7 * HID + lane * 2);
            float m0 = dis[i0], m1 = dis[i1], m2 = dis[i2], m3 = dis[i3];
            float m4 = dis[i4], m5 = dis[i5], m6 = dis[i6], m7 = dis[i7];
            acc0 += m0 * lo16(v0); acc1 += m0 * hi16(v0);
            acc0 += m1 * lo16(v1); acc1 += m1 * hi16(v1);
            acc0 += m2 * lo16(v2); acc1 += m2 * hi16(v2);
            acc0 += m3 * lo16(v3); acc1 += m3 * hi16(v3);
            acc0 += m4 * lo16(v4); acc1 += m4 * hi16(v4);
            acc0 += m5 * lo16(v5); acc1 += m5 * hi16(v5);
            acc0 += m6 * lo16(v6); acc1 += m6 * hi16(v6);
            acc0 += m7 * lo16(v7); acc1 += m7 * hi16(v7);
        }
        for (; e < e1; e++) {
            int s = csr[e];
            unsigned int v = *(const unsigned int*)(tin + (size_t)s * HID + lane * 2);
            float mm = dis[s];
            acc0 += mm * lo16(v); acc1 += mm * hi16(v);
        }
    }
    float o0 = di * acc0, o1 = di * acc1;
    if (bias) {
        if (flags[1]) { o0 += bf2f(((const unsigned short*)bias)[lane * 2]);
                        o1 += bf2f(((const unsigned short*)bias)[lane * 2 + 1]); }
        else          { o0 += ((const float*)bias)[lane * 2];
                        o1 += ((const float*)bias)[lane * 2 + 1]; }
    }
    if (relu) { o0 = fmaxf(o0, 0.f); o1 = fmaxf(o1, 0.f); }
    unsigned int pk = ((unsigned int)f2bf(o1) << 16) | (unsigned int)f2bf(o0);
    *(unsigned int*)(hout + (size_t)node * HID + lane * 2) = pk;
}

// ---------- layer 5: bf16 [NN,128] @ W5 [128,3] + b5 -> out (dtype per flags[1]) ----------

__global__ __launch_bounds__(256) void gemm5_kernel(const unsigned short* __restrict__ A,
                                                    const void* __restrict__ W5v,
                                                    const void* __restrict__ b5v,
                                                    const int* __restrict__ flags,
                                                    void* __restrict__ outv) {
    __shared__ float Ws[384];
    __shared__ float bs[3];
    int tid = threadIdx.x;
    int bf = flags[1];
    for (int idx = tid; idx < 384; idx += 256)
        Ws[idx] = bf ? bf2f(((const unsigned short*)W5v)[idx]) : ((const float*)W5v)[idx];
    if (tid < 3)
        bs[tid] = bf ? bf2f(((const unsigned short*)b5v)[tid]) : ((const float*)b5v)[tid];
    __syncthreads();
    int lane = tid & 63;
    int row = blockIdx.x * 4 + (tid >> 6);
    float a0 = bf2f(A[(size_t)row * HID + lane]);
    float a1 = bf2f(A[(size_t)row * HID + 64 + lane]);
    float c0 = a0 * Ws[lane * 3 + 0] + a1 * Ws[(lane + 64) * 3 + 0];
    float c1 = a0 * Ws[lane * 3 + 1] + a1 * Ws[(lane + 64) * 3 + 1];
    float c2 = a0 * Ws[lane * 3 + 2] + a1 * Ws[(lane + 64) * 3 + 2];
#pragma unroll
    for (int o = 32; o > 0; o >>= 1) {
        c0 += __shfl_down(c0, o);
        c1 += __shfl_down(c1, o);
        c2 += __shfl_down(c2, o);
    }
    if (lane == 0) {
        c0 += bs[0]; c1 += bs[1]; c2 += bs[2];
        if (bf) {
            unsigned short* out = (unsigned short*)outv;
            out[(size_t)row * 3 + 0] = f2bf(c0);
            out[(size_t)row * 3 + 1] = f2bf(c1);
            out[(size_t)row * 3 + 2] = f2bf(c2);
        } else {
            float* out = (float*)outv;
            out[(size_t)row * 3 + 0] = c0;
            out[(size_t)row * 3 + 1] = c1;
            out[(size_t)row * 3 + 2] = c2;
        }
    }
}

extern "C" void kernel_launch(void* const* d_in, const int* in_sizes, int n_in,
                              void* d_out, int out_size, void* d_ws, size_t ws_size,
                              hipStream_t stream) {
    const void* x = nullptr; const int* ei = nullptr;
    const void* W1 = nullptr; const void* W5 = nullptr; const void* b5 = nullptr;
    const void* Wmid[3] = {nullptr, nullptr, nullptr};
    const void* bvec[4] = {nullptr, nullptr, nullptr, nullptr};
    int nw = 0, nb = 0;
    for (int i = 0; i < n_in; i++) {
        int s = in_sizes[i];
        if      (s == 50000000) x = d_in[i];
        else if (s == 3200000)  ei = (const int*)d_in[i];
        else if (s == 64000)    W1 = d_in[i];
        else if (s == 16384)  { if (nw < 3) Wmid[nw++] = d_in[i]; }
        else if (s == 384)      W5 = d_in[i];
        else if (s == 128)    { if (nb < 4) bvec[nb++] = d_in[i]; }
        else if (s == 3)        b5 = d_in[i];
    }
    if (!x || !ei || !W1 || !W5 || !b5 || nw < 3 || nb < 4) return;

    char* p = (char*)d_ws;
    auto alloc = [&](size_t bytes) { char* q = p; p += (bytes + 255) & ~(size_t)255; return (void*)q; };
    int*   flags = (int*)alloc(256);
    float* dis   = (float*)alloc((size_t)NNP * 4);
    int*   cnt   = (int*)alloc((size_t)NN * 4);
    int*   off   = (int*)alloc((size_t)(NN + 1) * 4);
    int*   bsum  = (int*)alloc(128 * 4);
    int*   rank  = (int*)alloc((size_t)NE * 4);
    int*   csr   = (int*)alloc((size_t)NE * 4);
    unsigned short* Wt1 = (unsigned short*)alloc((size_t)128 * 512 * 2);
    unsigned short* Wt2 = (unsigned short*)alloc((size_t)128 * 128 * 2);
    unsigned short* Wt3 = (unsigned short*)alloc((size_t)128 * 128 * 2);
    unsigned short* Wt4 = (unsigned short*)alloc((size_t)128 * 128 * 2);
    unsigned short* T   = (unsigned short*)alloc((size_t)NNP * HID * 2);
    unsigned short* H   = (unsigned short*)alloc((size_t)NNP * HID * 2);

    // graph build + weight transposes
    GCNLarge_20761871909627_kernel<<<(NN + 255) / 256, 256, 0, stream>>>(cnt, NN);
    detect_kernel<<<1, 64, 0, stream>>>(ei, (const unsigned int*)x, flags);
    wt_kernel<<<256, 256, 0, stream>>>(W1, flags, Wt1, FIN, 512, 128 * 512);
    wt_kernel<<<64, 256, 0, stream>>>(Wmid[0], flags, Wt2, HID, 128, 128 * 128);
    wt_kernel<<<64, 256, 0, stream>>>(Wmid[1], flags, Wt3, HID, 128, 128 * 128);
    wt_kernel<<<64, 256, 0, stream>>>(Wmid[2], flags, Wt4, HID, 128, 128 * 128);
    count_kernel<<<(NE + 1023) / 1024, 256, 0, stream>>>(ei, flags, cnt, rank);
    dis_kernel<<<(NNP + 255) / 256, 256, 0, stream>>>(cnt, dis);
    scan1_kernel<<<98, 1024, 0, stream>>>(cnt, off, bsum);
    scan2_kernel<<<1, 64, 0, stream>>>(bsum, 98);
    scan3_kernel<<<98, 1024, 0, stream>>>(off, bsum);
    place_kernel<<<(NE + 1023) / 1024, 256, 0, stream>>>(ei, flags, off, rank, csr);

    // layer 1
    gemm1g_kernel<<<NNP / 64, 256, 0, stream>>>(x, Wt1, dis, flags, T);
    aggb_kernel<<<NN / 4, 256, 0, stream>>>(T, off, csr, dis, bvec[0], flags, H, 1, 0);
    // layers 2-4 (T/H ping-pong), 391 blocks x 4 tiles x 64 rows = NNP
    gemmWr_kernel<<<NNP / 256, 256, 0, stream>>>(H, Wt2, dis, T);
    aggb_kernel<<<NN / 4, 256, 0, stream>>>(T, off, csr, dis, bvec[1], flags, H, 1, 0);
    gemmWr_kernel<<<NNP / 256, 256, 0, stream>>>(H, Wt3, dis, T);
    aggb_kernel<<<NN / 4, 256, 0, stream>>>(T, off, csr, dis, bvec[2], flags, H, 1, 0);
    gemmWr_kernel<<<NNP / 256, 256, 0, stream>>>(H, Wt4, dis, T);
    aggb_kernel<<<NN / 4, 256, 0, stream>>>(T, off, csr, dis, bvec[3], flags, H, 1, 0);
    // layer 5: aggregate first (linearity), then small GEMM
    aggb_kernel<<<NN / 4, 256, 0, stream>>>(H, off, csr, dis, nullptr, flags, T, 0, 1);
    gemm5_kernel<<<NN / 4, 256, 0, stream>>>(T, W5, b5, flags, d_out);
}